// Round 4
// baseline (371.475 us; speedup 1.0000x reference)
//
#include <hip/hip_runtime.h>
#include <math.h>

// Problem constants
#define BB 4
#define NN 8192
#define CC 64
#define KK 16
#define HH 64
#define NPTS (BB*NN)   // 32768
#define EPSBN 1e-5f
#define CAP 64         // candidate buffer per query (fp64 refine picks 16)
#define NCELL 4096     // 16^3 Morton cells
#define CHN 128        // chunks per batch
#define CHSZ 64        // points per chunk

// ---------------- ws layout (float offsets) ----------------
#define OFF_XYZW  0
#define OFF_PW1AT 131072
#define OFF_PW1BT 135168
#define OFF_PWVAT 139264
#define OFF_PWOT  143360
#define OFF_RELW  147456
#define OFF_STATS 147840
#define OFF_IDX   148224      // idx: 32768*16 ints (SORTED-space neighbor ids)
#define OFF_OPRE  672512      // [32768][64] o_pre, ORIGINAL layout (old OUTV region)
#define OFF_SX4   2769664     // sorted xyzw [4][8192] float4
#define OFF_SID   2900736     // sorted->orig ids [4][8192] int
#define OFF_HIST  2933504     // [4][4096] int
#define OFF_RANK  2950912     // orig->sorted rank [4][8192] int
#define OFF_PH    2983680     // PH2 [256][256] h/v-stat buckets
#define OFF_PO    3049216     // PO2 [256][128] o-stat buckets
#define OFF_BB    3606272     // bbmin[512] f4 (2048) + bbmax[512] f4 (2048)
#define OFF_TAU   3610368     // tau16 per sorted point [32768] floats
#define OFF_F1    4866816     // SORTED layout
#define OFF_F2    6963968     // SORTED layout
#define OFF_FV    9061120     // SORTED layout

__device__ __forceinline__ int morton_cell(float x, float y, float z) {
    int cx = (int)floorf((x + 4.f) * 2.f);
    int cy = (int)floorf((y + 4.f) * 2.f);
    int cz = (int)floorf((z + 4.f) * 2.f);
    cx = cx < 0 ? 0 : (cx > 15 ? 15 : cx);
    cy = cy < 0 ? 0 : (cy > 15 ? 15 : cy);
    cz = cz < 0 ? 0 : (cz > 15 ? 15 : cz);
    int ex = (cx & 1) | ((cx & 2) << 2) | ((cx & 4) << 4) | ((cx & 8) << 6);
    int ey = (cy & 1) | ((cy & 2) << 2) | ((cy & 4) << 4) | ((cy & 8) << 6);
    int ez = (cz & 1) | ((cz & 2) << 2) | ((cz & 4) << 4) | ((cz & 8) << 6);
    return ex | (ey << 1) | (ez << 2);
}

__device__ __forceinline__ float distf(float4 me, float jx, float jy, float jz, float jw) {
    float dot = fmaf(me.z, jz, fmaf(me.y, jy, me.x * jx));
    return fmaf(-2.f, dot, me.w) + jw;
}

__device__ __forceinline__ float mind2(float4 me, float4 bmin, float4 bmax) {
    float dx = fmaxf(fmaxf(bmin.x - me.x, me.x - bmax.x), 0.f);
    float dy = fmaxf(fmaxf(bmin.y - me.y, me.y - bmax.y), 0.f);
    float dz = fmaxf(fmaxf(bmin.z - me.z, me.z - bmax.z), 0.f);
    return fmaf(dx, dx, fmaf(dy, dy, dz * dz));
}

__device__ __forceinline__ int mbcnt64(unsigned long long m) {
    return __builtin_amdgcn_mbcnt_hi((unsigned int)(m >> 32),
           __builtin_amdgcn_mbcnt_lo((unsigned int)m, 0));
}

__device__ __forceinline__ unsigned long long shflx_u64(unsigned long long v, int m) {
    int lo = __shfl_xor((int)(unsigned int)v, m, 64);
    int hi = __shfl_xor((int)(unsigned int)(v >> 32), m, 64);
    return ((unsigned long long)(unsigned int)hi << 32) | (unsigned int)lo;
}

__global__ __launch_bounds__(256) void k_prep(
    const float* __restrict__ xyz, const float* __restrict__ W1,
    const float* __restrict__ Wv, const float* __restrict__ Wo,
    float* __restrict__ xyzw, int* __restrict__ hist,
    float* __restrict__ pw1aT, float* __restrict__ pw1bT,
    float* __restrict__ pwvaT, float* __restrict__ pwoT, float* __restrict__ relw,
    float* __restrict__ stats)
{
    int t = threadIdx.x;
    int bid = blockIdx.x;
    if (bid < 128) {
        int pt = bid * 256 + t;
        int b = pt >> 13, n = pt & 8191;
        const float* xb = xyz + (unsigned)b * 3 * NN;
        float x = xb[n], y = xb[NN + n], z = xb[2 * NN + n];
        float sq = __fadd_rn(__fadd_rn(__fmul_rn(x, x), __fmul_rn(y, y)), __fmul_rn(z, z));
        ((float4*)xyzw)[pt] = make_float4(x, y, z, sq);
        atomicAdd(&hist[b * NCELL + morton_cell(x, y, z)], 1);
    } else {
        for (int e = t; e < 4096; e += 256) {
            int c = e >> 6, o = e & 63;
            pw1aT[e] = W1[o * 131 + c];
            pw1bT[e] = W1[o * 131 + 64 + c];
            pwvaT[e] = Wv[o * 67 + c];
            pwoT[e]  = Wo[o * 64 + c];
        }
        for (int e = t; e < 384; e += 256) {
            int d = e >> 6, o = e & 63;
            relw[e] = (d < 3) ? W1[o * 131 + 128 + d] : Wv[o * 67 + 64 + (d - 3)];
            stats[e] = 0.0f;
        }
    }
}

// Exclusive scan of per-batch 4096-bin histogram (in place), one block per batch.
__global__ __launch_bounds__(256) void k_scan(int* __restrict__ hist) {
    __shared__ int part[256];
    int b = blockIdx.x, t = threadIdx.x;
    int* h = hist + b * NCELL;
    int loc[16]; int s = 0;
#pragma unroll
    for (int i = 0; i < 16; i++) { loc[i] = h[t * 16 + i]; s += loc[i]; }
    part[t] = s;
    __syncthreads();
    for (int off = 1; off < 256; off <<= 1) {
        int v = (t >= off) ? part[t - off] : 0;
        __syncthreads();
        part[t] += v;
        __syncthreads();
    }
    int run = (t > 0) ? part[t - 1] : 0;
#pragma unroll
    for (int i = 0; i < 16; i++) { int c = loc[i]; h[t * 16 + i] = run; run += c; }
}

__global__ __launch_bounds__(256) void k_scatter(
    const float4* __restrict__ xyzw, int* __restrict__ off,
    float4* __restrict__ sx4, int* __restrict__ sid, int* __restrict__ rank)
{
    int pt = blockIdx.x * 256 + threadIdx.x;
    int b = pt >> 13, n = pt & 8191;
    float4 p = xyzw[pt];
    int cell = morton_cell(p.x, p.y, p.z);
    int dst = atomicAdd(&off[b * NCELL + cell], 1);
    sx4[(b << 13) + dst] = p;
    sid[(b << 13) + dst] = n;
    rank[pt] = dst;
}

// Per-chunk bbox over 64 sorted points. One wave per chunk; 512 chunks total.
__global__ __launch_bounds__(256) void k_bbox(
    const float4* __restrict__ sx4, float4* __restrict__ bbmin, float4* __restrict__ bbmax)
{
    int t = threadIdx.x, lane = t & 63, wl = t >> 6;
    int ch = blockIdx.x * 4 + wl;             // 0..511
    float4 p = sx4[ch * CHSZ + lane];
    float mnx = p.x, mny = p.y, mnz = p.z, mxx = p.x, mxy = p.y, mxz = p.z;
#pragma unroll
    for (int o = 32; o >= 1; o >>= 1) {
        mnx = fminf(mnx, __shfl_xor(mnx, o, 64)); mxx = fmaxf(mxx, __shfl_xor(mxx, o, 64));
        mny = fminf(mny, __shfl_xor(mny, o, 64)); mxy = fmaxf(mxy, __shfl_xor(mxy, o, 64));
        mnz = fminf(mnz, __shfl_xor(mnz, o, 64)); mxz = fmaxf(mxz, __shfl_xor(mxz, o, 64));
    }
    if (lane == 0) {
        bbmin[ch] = make_float4(mnx, mny, mnz, 0.f);
        bbmax[ch] = make_float4(mxx, mxy, mxz, 0.f);
    }
}

// Per-point tau16: exact 16th-smallest distance (incl. self) within the point's
// own 64-point Morton chunk. One wave per chunk; 512 waves total. Replaces the
// per-QUERY 21-stage window sort in k_knn with per-CHUNK work (64x fewer sorts).
// Uses the same fp32 distf formula as k_knn's scan so tau >= those 16 dists
// holds bit-exactly.
__global__ __launch_bounds__(256) void k_tau(
    const float4* __restrict__ sx4, float* __restrict__ tauPt)
{
    int t = threadIdx.x, lane = t & 63, wl = t >> 6;
    int ch = blockIdx.x * 4 + wl;             // 0..511
    float4 p = sx4[ch * CHSZ + lane];         // my point (w = |p|^2)
    const float INF = 3.402823466e38f;
    float f0=INF,f1=INF,f2=INF,f3=INF,f4=INF,f5=INF,f6=INF,f7=INF;
    float f8=INF,f9=INF,f10=INF,f11=INF,f12=INF,f13=INF,f14=INF,f15=INF;
    float mx = INF;
    for (int j = 0; j < 64; j++) {
        float jx = __int_as_float(__builtin_amdgcn_readlane(__float_as_int(p.x), j));
        float jy = __int_as_float(__builtin_amdgcn_readlane(__float_as_int(p.y), j));
        float jz = __int_as_float(__builtin_amdgcn_readlane(__float_as_int(p.z), j));
        float jw = __int_as_float(__builtin_amdgcn_readlane(__float_as_int(p.w), j));
        float d = distf(p, jx, jy, jz, jw);
        bool rep = (d < mx);
        if (__any(rep)) {
            // replace current max with d (first match only), then recompute max
            bool done = !rep;
#define REP(F) { bool hit = !done && (F == mx); F = hit ? d : F; done = done || hit; }
            REP(f0) REP(f1) REP(f2) REP(f3) REP(f4) REP(f5) REP(f6) REP(f7)
            REP(f8) REP(f9) REP(f10) REP(f11) REP(f12) REP(f13) REP(f14) REP(f15)
#undef REP
            float m0 = fmaxf(fmaxf(fmaxf(f0, f1), fmaxf(f2, f3)),
                             fmaxf(fmaxf(f4, f5), fmaxf(f6, f7)));
            float m1 = fmaxf(fmaxf(fmaxf(f8, f9), fmaxf(f10, f11)),
                             fmaxf(fmaxf(f12, f13), fmaxf(f14, f15)));
            mx = fmaxf(m0, m1);
        }
    }
    tauPt[ch * CHSZ + lane] = mx;             // 16th smallest (self included)
}

// Per-point GEMVs, output scattered to SORTED layout via rank.
__global__ __launch_bounds__(256) void k_F(
    const float* __restrict__ feats, const float* __restrict__ b1, const float* __restrict__ bv,
    const float* __restrict__ pw1aT, const float* __restrict__ pw1bT, const float* __restrict__ pwvaT,
    const int* __restrict__ rank,
    float* __restrict__ F1, float* __restrict__ F2, float* __restrict__ FV)
{
    int t = threadIdx.x;
    int lane = t & 63;
    int wave = t >> 6;
    int pt0 = blockIdx.x * 64 + wave * 16;
    int b   = __builtin_amdgcn_readfirstlane(pt0 >> 13);
    int n0  = __builtin_amdgcn_readfirstlane(pt0 & 8191);
    const float* fb = feats + (unsigned)b * CC * NN;
    float accA[16], accB[16], accV[16];
    float bb1 = b1[lane], bbv = bv[lane];
#pragma unroll
    for (int p = 0; p < 16; p++) { accA[p] = bb1; accB[p] = 0.f; accV[p] = bbv; }
    for (int c = 0; c < 64; c++) {
        float wA = pw1aT[c * 64 + lane];
        float wB = pw1bT[c * 64 + lane];
        float wV = pwvaT[c * 64 + lane];
        const float* fr = fb + (unsigned)c * NN + n0;
#pragma unroll
        for (int p = 0; p < 16; p++) {
            float f = fr[p];
            accA[p] = fmaf(wA, f, accA[p]);
            accB[p] = fmaf(wB, f, accB[p]);
            accV[p] = fmaf(wV, f, accV[p]);
        }
    }
#pragma unroll
    for (int p = 0; p < 16; p++) {
        unsigned dst = ((unsigned)b << 13) + (unsigned)rank[pt0 + p];  // wave-uniform
        F1[dst * 64u + lane] = accA[p];
        F2[dst * 64u + lane] = accB[p];
        FV[dst * 64u + lane] = accV[p];
    }
}

// One ballot-parallel candidate-collection pass at threshold tcur.
// Returns TOTAL count of points with d <= tcur in passing chunks (may exceed
// CAP); stores the first CAP into wc.
__device__ __forceinline__ int scan_pass(
    const float4* __restrict__ sb, float4 me, float md0, float md1,
    float tcur, int* wc, int lane)
{
    unsigned long long bm0 = __ballot(md0 <= tcur);
    unsigned long long bm1 = __ballot(md1 <= tcur);
    int cnt = 0;
    int c0 = -1;
    if (bm0)      { c0 = __builtin_ctzll(bm0); bm0 &= bm0 - 1; }
    else if (bm1) { c0 = 64 + __builtin_ctzll(bm1); bm1 &= bm1 - 1; }
    float4 p0 = make_float4(0.f, 0.f, 0.f, 0.f);
    if (c0 >= 0) p0 = sb[(unsigned)(c0 * CHSZ + lane)];
    while (c0 >= 0) {
        int c1 = -1;
        if (bm0)      { c1 = __builtin_ctzll(bm0); bm0 &= bm0 - 1; }
        else if (bm1) { c1 = 64 + __builtin_ctzll(bm1); bm1 &= bm1 - 1; }
        float4 p1 = p0;
        if (c1 >= 0) p1 = sb[(unsigned)(c1 * CHSZ + lane)];
        float dd = distf(me, p0.x, p0.y, p0.z, p0.w);
        bool hit = (dd <= tcur);
        unsigned long long m2 = __ballot(hit);
        if (hit) {
            int slot = cnt + mbcnt64(m2);
            if (slot < CAP) wc[slot] = c0 * CHSZ + lane;
        }
        cnt += __popcll(m2);
        c0 = c1; p0 = p1;
    }
    return cnt;
}

// Rare^2 safety net: exact top-32 sorted-insert over chunks within thi.
// Valid because cnt(thi) > CAP >= 16 implies all true top-16 lie within thi.
__device__ __attribute__((noinline)) void knn_safety(
    const float4* __restrict__ sb, float4 me, float md0, float md1,
    float thi, int lane, int* wc)
{
    const float INF = 3.402823466e38f;
    float val = INF;
    int vid = 0;              // all 32 slots get real ids (first chunk floods)
    float tau2 = INF;
    float thiA = thi * 1.0001f + 1e-5f;
    unsigned long long fb0 = __ballot(md0 <= thiA);
    unsigned long long fb1 = __ballot(md1 <= thiA);
    bool lt32 = (lane < 32);
    while (fb0 | fb1) {
        int c;
        if (fb0) { c = __builtin_ctzll(fb0); fb0 &= fb0 - 1; }
        else     { c = 64 + __builtin_ctzll(fb1); fb1 &= fb1 - 1; }
        float4 p = sb[(unsigned)(c * CHSZ + lane)];
        float dd = distf(me, p.x, p.y, p.z, p.w);
        unsigned long long m = __ballot(dd < tau2);
        while (m) {
            int hl = __builtin_ctzll(m); m &= m - 1;
            float dn = __int_as_float(
                __builtin_amdgcn_readlane(__float_as_int(dd), hl));
            int jn = c * CHSZ + hl;
            unsigned long long bl = __ballot(val < dn);
            int pos2 = __popcll(bl);
            float sv = __shfl_up(val, 1, 64);
            int   sj = __shfl_up(vid, 1, 64);
            float nv = (lane > pos2) ? sv : val; nv = (lane == pos2) ? dn : nv;
            int   nj = (lane > pos2) ? sj : vid; nj = (lane == pos2) ? jn : nj;
            val = lt32 ? nv : val;
            vid = lt32 ? nj : vid;
            tau2 = __int_as_float(__builtin_amdgcn_readlane(__float_as_int(val), 31));
        }
    }
    if (lt32) wc[lane] = vid;
}

// Fused KNN + fp64 refine + h/v BN-stats. ONE query per wave, XCD-swizzled.
// Round-4: NO per-query window sort -- tau16 comes precomputed from k_tau
// (per-chunk all-pairs). Overflow handled by predictive tau-shrink rescans
// (cnt ~ tau^{3/2}) instead of the serial sorted-insert that caused the long
// tail; serial path kept only as a rare^2 safety net.
__global__ __launch_bounds__(128) void k_knn(
    const float4* __restrict__ sx4, const int* __restrict__ sid,
    const float4* __restrict__ bbmin, const float4* __restrict__ bbmax,
    const float* __restrict__ tauPt,
    const float* __restrict__ F1, const float* __restrict__ F2, const float* __restrict__ FV,
    const float* __restrict__ relw,
    int* __restrict__ idx, float* __restrict__ ph2)
{
    __shared__ int cand[2][CAP];
    int lane = threadIdx.x & 63;
    int wl = threadIdx.x >> 6;
    int bx = blockIdx.x;                       // 16384 blocks
    int vb = (bx & 7) * 2048 + (bx >> 3);      // XCD-aware swizzle (bijective)
    int gq = vb * 2 + wl;
    int b = __builtin_amdgcn_readfirstlane(gq >> 13);
    int qs = gq & 8191;
    const float4* sb = sx4 + ((unsigned)b << 13);
    const int* ib = sid + ((unsigned)b << 13);
    float4 me = sb[qs];                       // wave-uniform
    int* wc = cand[wl];

    float tau = tauPt[gq];                    // wave-uniform scalar
    float tauA = tau * 1.0001f + 1e-5f;
    float md0 = mind2(me, bbmin[b * CHN + lane], bbmax[b * CHN + lane]);
    float md1 = mind2(me, bbmin[b * CHN + 64 + lane], bbmax[b * CHN + 64 + lane]);

    int cnt = scan_pass(sb, me, md0, md1, tauA, wc, lane);

    if (__builtin_expect(cnt > CAP, 0)) {
        // predictive tau-shrink: cnt(tau) ~ tau^{3/2}; target ~48 candidates.
        // invariant: cnt(thi) > CAP (so >=16 points within thi -> any accepted
        // tau' with cnt' >= 16 contains the true top-16).
        float tlo = 0.f, thi = tauA;
        int chi = cnt;
        bool ok = false;
        for (int at = 0; at < 4; at++) {
            float tr = thi * __powf(48.f / (float)chi, 0.6666667f);
            if (!(tr > tlo && tr < thi)) tr = 0.5f * (tlo + thi);
            int c = scan_pass(sb, me, md0, md1, tr, wc, lane);
            if (c > CAP)     { thi = tr; chi = c; }
            else if (c < 16) { tlo = tr; }
            else             { cnt = c; ok = true; break; }
        }
        if (!ok) { knn_safety(sb, me, md0, md1, thi, lane, wc); cnt = 32; }
    }

    // fp64 refine as single u64 key partial top-16 selection (16 stages)
    unsigned long long key;
    {
        double mx = (double)me.x, my = (double)me.y, mz = (double)me.z;
        double msq = (mx * mx + my * my) + mz * mz;
        if (lane < cnt) {
            int j = wc[lane];
            float4 cj = sb[(unsigned)j];
            double jx = (double)cj.x, jy = (double)cj.y, jz = (double)cj.z;
            double dot = (mx * jx + my * jy) + mz * jz;
            double sqj = (jx * jx + jy * jy) + jz * jz;
            double dd = (-2.0 * dot + msq) + sqj;
            dd = fmax(dd, 0.0);               // guard sign bit for u64 ordering
            unsigned long long pay = (unsigned long long)(unsigned int)((ib[j] << 13) | j);
            key = ((unsigned long long)__double_as_longlong(dd) & ~0x3FFFFFFULL) | pay;
        } else {
            key = (0x7FFULL << 52) | (unsigned int)lane;   // > any valid key, unique
        }
    }

#define CE(MASK, WMIN) do {                                                   \
        unsigned long long ok2 = shflx_u64(key, (MASK));                      \
        bool ol = ok2 < key;                                                  \
        bool tk = (WMIN) ? ol : !ol;                                          \
        key = tk ? ok2 : key;                                                 \
    } while (0)

    // stage A: sort 16-lane groups, alternating direction (10 exchanges)
#pragma unroll
    for (int k2 = 2; k2 <= 16; k2 <<= 1) {
#pragma unroll
        for (int j2 = k2 >> 1; j2 >= 1; j2 >>= 1) {
            bool wantMin = (((lane & j2) == 0) == ((lane & k2) == 0));
            CE(j2, wantMin);
        }
    }
    // stage B: bitonic halving: lanes 0..15 / 32..47 keep min-16
    CE(16, ((lane & 16) == 0));
    // stage C: sort the two bitonic 16-seqs ascending (4 exchanges)
#pragma unroll
    for (int j2 = 8; j2 >= 1; j2 >>= 1)
        CE(j2, ((lane & j2) == 0));
    // stage D: cross-merge sorted 16-sets: lane L (0..15) pairs with 47-L
    CE(47, true);
#undef CE

    int jw = (int)(key & 8191);               // sorted-space neighbor id (lanes 0..15)
    if (lane < 16) idx[(unsigned)gq * 16u + lane] = jw;

    // ---- fused h/v BN stats for this query's 16 neighbors (4-wide batches) ----
    float rw0 = relw[0 * 64 + lane], rw1 = relw[1 * 64 + lane], rw2 = relw[2 * 64 + lane];
    float rw3 = relw[3 * 64 + lane], rw4 = relw[4 * 64 + lane], rw5 = relw[5 * 64 + lane];
    float F1v = F1[(unsigned)gq * 64u + lane];
    unsigned gb = (unsigned)b << 13;
    float sh = 0.f, sh2 = 0.f, sv = 0.f, sv2 = 0.f;
#pragma unroll
    for (int kb = 0; kb < 4; kb++) {
        float4 cjA[4]; float f2A[4], fvA[4];
#pragma unroll
        for (int jj = 0; jj < 4; jj++) {
            int g = __builtin_amdgcn_readlane(jw, kb * 4 + jj);   // k-th neighbor id
            cjA[jj] = sb[(unsigned)g];
            unsigned go = (gb + (unsigned)g) * 64u + lane;
            f2A[jj] = F2[go];
            fvA[jj] = FV[go];
        }
#pragma unroll
        for (int jj = 0; jj < 4; jj++) {
            float rx = cjA[jj].x - me.x, ry = cjA[jj].y - me.y, rz = cjA[jj].z - me.z;
            float h = F1v + f2A[jj];
            h = fmaf(rw0, rx, h); h = fmaf(rw1, ry, h); h = fmaf(rw2, rz, h);
            float v = fvA[jj];
            v = fmaf(rw3, rx, v); v = fmaf(rw4, ry, v); v = fmaf(rw5, rz, v);
            sh += h; sh2 = fmaf(h, h, sh2);
            sv += v; sv2 = fmaf(v, v, sv2);
        }
    }
    float* bucket = ph2 + (unsigned)(bx & 255) * 256u;
    atomicAdd(&bucket[lane], sh);
    atomicAdd(&bucket[64 + lane], sh2);
    atomicAdd(&bucket[128 + lane], sv);
    atomicAdd(&bucket[192 + lane], sv2);
}

// Reduce PH2[256][256] -> stats[0..255]. 8 blocks; 8 atomics/addr.
__global__ __launch_bounds__(256) void k_red1(
    const float* __restrict__ ph2, float* __restrict__ stats)
{
    int t = threadIdx.x, p = blockIdx.x;
    float acc = 0.f;
    for (int i = 0; i < 32; i++)
        acc += ph2[(unsigned)(p * 32 + i) * 256u + t];
    atomicAdd(&stats[t], acc);
}

// Attention + fused Wo matvec + o-stats. SORTED space, XCD-swizzled.
__global__ __launch_bounds__(256) void k_attn(
    const float4* __restrict__ sx4, const int* __restrict__ sid,
    const int* __restrict__ idx,
    const float* __restrict__ F1, const float* __restrict__ F2, const float* __restrict__ FV,
    const float* __restrict__ relw, const float* __restrict__ stats,
    const float* __restrict__ g1, const float* __restrict__ be1,
    const float* __restrict__ W2, const float* __restrict__ b2,
    const float* __restrict__ gv, const float* __restrict__ bev,
    const float* __restrict__ pwoT, const float* __restrict__ bo,
    float* __restrict__ opre, float* __restrict__ po2)
{
    __shared__ float lds_out[4][64];
    int t = threadIdx.x;
    int lane = t & 63;
    int wl = t >> 6;
    int bx = blockIdx.x;                      // 8192 blocks
    int vb = (bx & 7) * 1024 + (bx >> 3);     // XCD-aware swizzle
    int gq = vb * 4 + wl;                     // sorted-global query
    const float invM = 1.f / 524288.f;
    float hm = stats[lane] * invM, hq = stats[64 + lane] * invM;
    float s1 = g1[lane] * rsqrtf(hq - hm * hm + EPSBN);
    float t1 = be1[lane] - s1 * hm;
    float vm = stats[128 + lane] * invM, vq = stats[192 + lane] * invM;
    float sv = gv[lane] * rsqrtf(vq - vm * vm + EPSBN);
    float tv = bev[lane] - sv * vm;
    float rw0 = relw[0 * 64 + lane], rw1 = relw[1 * 64 + lane], rw2 = relw[2 * 64 + lane];
    float rw3 = relw[3 * 64 + lane], rw4 = relw[4 * 64 + lane], rw5 = relw[5 * 64 + lane];
    float w2v = W2[lane];
    float b2v = b2[0];
    float bov = bo[lane];

    int b = __builtin_amdgcn_readfirstlane(gq >> 13);
    const float4* sb = sx4 + ((unsigned)b << 13);
    float4 me = sb[(unsigned)(gq & 8191)];
    float F1v = F1[(unsigned)gq * 64u + lane];
    unsigned orig = ((unsigned)b << 13) + (unsigned)sid[gq];   // wave-uniform
    const int* ip = idx + (unsigned)gq * 16u;
    unsigned gb = (unsigned)b << 13;
    float ek[16], vk[16];
#pragma unroll
    for (int kb = 0; kb < 2; kb++) {
        float4 cjA[8]; float f2A[8], fvA[8];
#pragma unroll
        for (int jj = 0; jj < 8; jj++) {
            int gl = ip[kb * 8 + jj];
            cjA[jj] = sb[(unsigned)gl];
            unsigned go = (gb + (unsigned)gl) * 64u + lane;
            f2A[jj] = F2[go];
            fvA[jj] = FV[go];
        }
#pragma unroll
        for (int jj = 0; jj < 8; jj++) {
            int k = kb * 8 + jj;
            float rx = cjA[jj].x - me.x, ry = cjA[jj].y - me.y, rz = cjA[jj].z - me.z;
            float h = F1v + f2A[jj];
            h = fmaf(rw0, rx, h); h = fmaf(rw1, ry, h); h = fmaf(rw2, rz, h);
            float a = fmaxf(fmaf(s1, h, t1), 0.f);
            float v = fvA[jj];
            v = fmaf(rw3, rx, v); v = fmaf(rw4, ry, v); v = fmaf(rw5, rz, v);
            vk[k] = fmaxf(fmaf(sv, v, tv), 0.f);
            float lg = w2v * a;
#pragma unroll
            for (int off = 32; off >= 1; off >>= 1) lg += __shfl_xor(lg, off, 64);
            ek[k] = lg + b2v;
        }
    }
    float mx = ek[0];
#pragma unroll
    for (int k = 1; k < 16; k++) mx = fmaxf(mx, ek[k]);
    float ssum = 0.f;
#pragma unroll
    for (int k = 0; k < 16; k++) { float e = __expf(ek[k] - mx); ek[k] = e; ssum += e; }
    float acc = 0.f;
#pragma unroll
    for (int k = 0; k < 16; k++) acc = fmaf(ek[k], vk[k], acc);
    float ov = acc / ssum;

    // fused Wo matvec: wave-local LDS row; 4 accumulators break the 64-deep
    // serial fmaf chain
    lds_out[wl][lane] = ov;
    float op0 = bov, op1 = 0.f, op2 = 0.f, op3 = 0.f;
#pragma unroll
    for (int c = 0; c < 64; c += 4) {
        op0 = fmaf(pwoT[(c + 0) * 64 + lane], lds_out[wl][c + 0], op0);
        op1 = fmaf(pwoT[(c + 1) * 64 + lane], lds_out[wl][c + 1], op1);
        op2 = fmaf(pwoT[(c + 2) * 64 + lane], lds_out[wl][c + 2], op2);
        op3 = fmaf(pwoT[(c + 3) * 64 + lane], lds_out[wl][c + 3], op3);
    }
    float op = (op0 + op1) + (op2 + op3);
    opre[orig * 64u + lane] = op;

    float* bucket = po2 + (unsigned)(bx & 255) * 128u;
    atomicAdd(&bucket[lane], op);
    atomicAdd(&bucket[64 + lane], op * op);
}

// Reduce PO2[256][128] -> stats[256..383]. 8 blocks; 8 atomics/addr.
__global__ __launch_bounds__(256) void k_red2(
    const float* __restrict__ po2, float* __restrict__ stats)
{
    int t = threadIdx.x, p = blockIdx.x;
    if (t < 128) {
        float acc = 0.f;
        for (int i = 0; i < 32; i++)
            acc += po2[(unsigned)(p * 32 + i) * 128u + t];
        atomicAdd(&stats[256 + t], acc);
    }
}

// Final: BN(o)+relu + residual feats, transpose [B,N,C]->[B,C,N]
__global__ __launch_bounds__(256) void k_final(
    const float* __restrict__ opre, const float* __restrict__ stats,
    const float* __restrict__ go, const float* __restrict__ beo,
    const float* __restrict__ feats, float* __restrict__ out)
{
    __shared__ float tile[64][65];
    int t = threadIdx.x;
    int blk = blockIdx.x;
    int b = blk >> 7, n0 = (blk & 127) << 6;
#pragma unroll
    for (int i = 0; i < 16; i++) {
        int e = t + i * 256;
        int r = e >> 6, c = e & 63;
        tile[r][c] = opre[(unsigned)((b << 13) + n0 + r) * 64u + c];
    }
    __syncthreads();
    const float invM = 1.f / 32768.f;
    int lane = t & 63, wv = t >> 6;
#pragma unroll
    for (int i = 0; i < 16; i++) {
        int c = wv * 16 + i;
        float om = stats[256 + c] * invM, oq = stats[320 + c] * invM;
        float so = go[c] * rsqrtf(oq - om * om + EPSBN);
        float to = beo[c] - so * om;
        float val = fmaxf(fmaf(so, tile[lane][c], to), 0.f);
        unsigned oix = ((unsigned)b * 64 + c) * NN + n0 + lane;
        out[oix] = val + feats[oix];
    }
}

extern "C" void kernel_launch(void* const* d_in, const int* in_sizes, int n_in,
                              void* d_out, int out_size, void* d_ws, size_t ws_size,
                              hipStream_t stream)
{
    const float* xyz  = (const float*)d_in[0];
    const float* feats= (const float*)d_in[1];
    const float* W1   = (const float*)d_in[2];
    const float* b1   = (const float*)d_in[3];
    const float* g1   = (const float*)d_in[4];
    const float* be1  = (const float*)d_in[5];
    const float* W2   = (const float*)d_in[6];
    const float* b2   = (const float*)d_in[7];
    const float* Wv   = (const float*)d_in[8];
    const float* bv   = (const float*)d_in[9];
    const float* gv   = (const float*)d_in[10];
    const float* bev  = (const float*)d_in[11];
    const float* Wo   = (const float*)d_in[12];
    const float* bo   = (const float*)d_in[13];
    const float* go   = (const float*)d_in[14];
    const float* beo  = (const float*)d_in[15];

    float* ws = (float*)d_ws;
    float* xyzw  = ws + OFF_XYZW;
    float* pw1aT = ws + OFF_PW1AT;
    float* pw1bT = ws + OFF_PW1BT;
    float* pwvaT = ws + OFF_PWVAT;
    float* pwoT  = ws + OFF_PWOT;
    float* relw  = ws + OFF_RELW;
    float* stats = ws + OFF_STATS;
    int*   idx   = (int*)(ws + OFF_IDX);
    float* opre  = ws + OFF_OPRE;
    float4* sx4  = (float4*)(ws + OFF_SX4);
    int*   sid   = (int*)(ws + OFF_SID);
    int*   hist  = (int*)(ws + OFF_HIST);
    float4* bbmn = (float4*)(ws + OFF_BB);
    float4* bbmx = (float4*)(ws + OFF_BB + 2048);
    float* tauPt = ws + OFF_TAU;
    int*   rank  = (int*)(ws + OFF_RANK);
    float* ph2   = ws + OFF_PH;
    float* po2   = ws + OFF_PO;
    float* F1    = ws + OFF_F1;
    float* F2    = ws + OFF_F2;
    float* FV    = ws + OFF_FV;

    hipMemsetAsync(hist, 0, BB * NCELL * sizeof(int), stream);
    hipMemsetAsync(ph2, 0, (65536 + 32768) * sizeof(float), stream);  // PH2+PO2 contiguous
    k_prep<<<129, 256, 0, stream>>>(xyz, W1, Wv, Wo, xyzw, hist,
                                    pw1aT, pw1bT, pwvaT, pwoT, relw, stats);
    k_scan<<<4, 256, 0, stream>>>(hist);
    k_scatter<<<128, 256, 0, stream>>>((const float4*)xyzw, hist, sx4, sid, rank);
    k_bbox<<<128, 256, 0, stream>>>((const float4*)sx4, bbmn, bbmx);
    k_tau<<<128, 256, 0, stream>>>((const float4*)sx4, tauPt);
    k_F<<<512, 256, 0, stream>>>(feats, b1, bv, pw1aT, pw1bT, pwvaT, rank, F1, F2, FV);
    k_knn<<<NPTS / 2, 128, 0, stream>>>((const float4*)sx4, sid, bbmn, bbmx, tauPt,
                                        F1, F2, FV, relw, idx, ph2);
    k_red1<<<8, 256, 0, stream>>>(ph2, stats);
    k_attn<<<8192, 256, 0, stream>>>((const float4*)sx4, sid, idx, F1, F2, FV, relw, stats,
                                     g1, be1, W2, b2, gv, bev, pwoT, bo, opre, po2);
    k_red2<<<8, 256, 0, stream>>>(po2, stats);
    k_final<<<512, 256, 0, stream>>>(opre, stats, go, beo, feats, (float*)d_out);
}

// Round 6
// 310.684 us; speedup vs baseline: 1.1957x; 1.1957x over previous
//
#include <hip/hip_runtime.h>
#include <math.h>

// Problem constants
#define BB 4
#define NN 8192
#define CC 64
#define KK 16
#define HH 64
#define NPTS (BB*NN)   // 32768
#define EPSBN 1e-5f
#define CAP 64         // candidate buffer per query (fp64 refine picks 16)
#define NCELL 4096     // 16^3 Morton cells
#define CHN 128        // chunks per batch
#define CHSZ 64        // points per chunk

// ---------------- ws layout (float offsets) ----------------
#define OFF_XYZW  0
#define OFF_PW1AT 131072
#define OFF_PW1BT 135168
#define OFF_PWVAT 139264
#define OFF_PWOT  143360
#define OFF_RELW  147456
#define OFF_STATS 147840
#define OFF_IDX   148224      // idx: 32768*16 ints (SORTED-space neighbor ids)
#define OFF_OPRE  672512      // [32768][64] o_pre, ORIGINAL layout (old OUTV region)
#define OFF_SX4   2769664     // sorted xyzw [4][8192] float4
#define OFF_SID   2900736     // sorted->orig ids [4][8192] int
#define OFF_HIST  2933504     // [4][4096] int
#define OFF_RANK  2950912     // orig->sorted rank [4][8192] int
#define OFF_PH    2983680     // PH2 [256][256] h/v-stat buckets
#define OFF_PO    3049216     // PO2 [256][128] o-stat buckets
#define OFF_BB    3606272     // bbmin[512] f4 (2048) + bbmax[512] f4 (2048)
#define OFF_F1    4866816     // SORTED layout
#define OFF_F2    6963968     // SORTED layout
#define OFF_FV    9061120     // SORTED layout

__device__ __forceinline__ int morton_cell(float x, float y, float z) {
    int cx = (int)floorf((x + 4.f) * 2.f);
    int cy = (int)floorf((y + 4.f) * 2.f);
    int cz = (int)floorf((z + 4.f) * 2.f);
    cx = cx < 0 ? 0 : (cx > 15 ? 15 : cx);
    cy = cy < 0 ? 0 : (cy > 15 ? 15 : cy);
    cz = cz < 0 ? 0 : (cz > 15 ? 15 : cz);
    int ex = (cx & 1) | ((cx & 2) << 2) | ((cx & 4) << 4) | ((cx & 8) << 6);
    int ey = (cy & 1) | ((cy & 2) << 2) | ((cy & 4) << 4) | ((cy & 8) << 6);
    int ez = (cz & 1) | ((cz & 2) << 2) | ((cz & 4) << 4) | ((cz & 8) << 6);
    return ex | (ey << 1) | (ez << 2);
}

__device__ __forceinline__ float distf(float4 me, float jx, float jy, float jz, float jw) {
    float dot = fmaf(me.z, jz, fmaf(me.y, jy, me.x * jx));
    return fmaf(-2.f, dot, me.w) + jw;
}

__device__ __forceinline__ float mind2(float4 me, float4 bmin, float4 bmax) {
    float dx = fmaxf(fmaxf(bmin.x - me.x, me.x - bmax.x), 0.f);
    float dy = fmaxf(fmaxf(bmin.y - me.y, me.y - bmax.y), 0.f);
    float dz = fmaxf(fmaxf(bmin.z - me.z, me.z - bmax.z), 0.f);
    return fmaf(dx, dx, fmaf(dy, dy, dz * dz));
}

__device__ __forceinline__ int mbcnt64(unsigned long long m) {
    return __builtin_amdgcn_mbcnt_hi((unsigned int)(m >> 32),
           __builtin_amdgcn_mbcnt_lo((unsigned int)m, 0));
}

__device__ __forceinline__ unsigned long long shflx_u64(unsigned long long v, int m) {
    int lo = __shfl_xor((int)(unsigned int)v, m, 64);
    int hi = __shfl_xor((int)(unsigned int)(v >> 32), m, 64);
    return ((unsigned long long)(unsigned int)hi << 32) | (unsigned int)lo;
}

__global__ __launch_bounds__(256) void k_prep(
    const float* __restrict__ xyz, const float* __restrict__ W1,
    const float* __restrict__ Wv, const float* __restrict__ Wo,
    float* __restrict__ xyzw, int* __restrict__ hist,
    float* __restrict__ pw1aT, float* __restrict__ pw1bT,
    float* __restrict__ pwvaT, float* __restrict__ pwoT, float* __restrict__ relw,
    float* __restrict__ stats)
{
    int t = threadIdx.x;
    int bid = blockIdx.x;
    if (bid < 128) {
        int pt = bid * 256 + t;
        int b = pt >> 13, n = pt & 8191;
        const float* xb = xyz + (unsigned)b * 3 * NN;
        float x = xb[n], y = xb[NN + n], z = xb[2 * NN + n];
        float sq = __fadd_rn(__fadd_rn(__fmul_rn(x, x), __fmul_rn(y, y)), __fmul_rn(z, z));
        ((float4*)xyzw)[pt] = make_float4(x, y, z, sq);
        atomicAdd(&hist[b * NCELL + morton_cell(x, y, z)], 1);
    } else {
        for (int e = t; e < 4096; e += 256) {
            int c = e >> 6, o = e & 63;
            pw1aT[e] = W1[o * 131 + c];
            pw1bT[e] = W1[o * 131 + 64 + c];
            pwvaT[e] = Wv[o * 67 + c];
            pwoT[e]  = Wo[o * 64 + c];
        }
        for (int e = t; e < 384; e += 256) {
            int d = e >> 6, o = e & 63;
            relw[e] = (d < 3) ? W1[o * 131 + 128 + d] : Wv[o * 67 + 64 + (d - 3)];
            stats[e] = 0.0f;
        }
    }
}

// Exclusive scan of per-batch 4096-bin histogram (in place), one block per batch.
__global__ __launch_bounds__(256) void k_scan(int* __restrict__ hist) {
    __shared__ int part[256];
    int b = blockIdx.x, t = threadIdx.x;
    int* h = hist + b * NCELL;
    int loc[16]; int s = 0;
#pragma unroll
    for (int i = 0; i < 16; i++) { loc[i] = h[t * 16 + i]; s += loc[i]; }
    part[t] = s;
    __syncthreads();
    for (int off = 1; off < 256; off <<= 1) {
        int v = (t >= off) ? part[t - off] : 0;
        __syncthreads();
        part[t] += v;
        __syncthreads();
    }
    int run = (t > 0) ? part[t - 1] : 0;
#pragma unroll
    for (int i = 0; i < 16; i++) { int c = loc[i]; h[t * 16 + i] = run; run += c; }
}

__global__ __launch_bounds__(256) void k_scatter(
    const float4* __restrict__ xyzw, int* __restrict__ off,
    float4* __restrict__ sx4, int* __restrict__ sid, int* __restrict__ rank)
{
    int pt = blockIdx.x * 256 + threadIdx.x;
    int b = pt >> 13, n = pt & 8191;
    float4 p = xyzw[pt];
    int cell = morton_cell(p.x, p.y, p.z);
    int dst = atomicAdd(&off[b * NCELL + cell], 1);
    sx4[(b << 13) + dst] = p;
    sid[(b << 13) + dst] = n;
    rank[pt] = dst;
}

// Per-chunk bbox over 64 sorted points. One wave per chunk; 512 chunks total.
__global__ __launch_bounds__(256) void k_bbox(
    const float4* __restrict__ sx4, float4* __restrict__ bbmin, float4* __restrict__ bbmax)
{
    int t = threadIdx.x, lane = t & 63, wl = t >> 6;
    int ch = blockIdx.x * 4 + wl;             // 0..511
    float4 p = sx4[ch * CHSZ + lane];
    float mnx = p.x, mny = p.y, mnz = p.z, mxx = p.x, mxy = p.y, mxz = p.z;
#pragma unroll
    for (int o = 32; o >= 1; o >>= 1) {
        mnx = fminf(mnx, __shfl_xor(mnx, o, 64)); mxx = fmaxf(mxx, __shfl_xor(mxx, o, 64));
        mny = fminf(mny, __shfl_xor(mny, o, 64)); mxy = fmaxf(mxy, __shfl_xor(mxy, o, 64));
        mnz = fminf(mnz, __shfl_xor(mnz, o, 64)); mxz = fmaxf(mxz, __shfl_xor(mxz, o, 64));
    }
    if (lane == 0) {
        bbmin[ch] = make_float4(mnx, mny, mnz, 0.f);
        bbmax[ch] = make_float4(mxx, mxy, mxz, 0.f);
    }
}

// Per-point GEMVs, output scattered to SORTED layout via rank.
__global__ __launch_bounds__(256) void k_F(
    const float* __restrict__ feats, const float* __restrict__ b1, const float* __restrict__ bv,
    const float* __restrict__ pw1aT, const float* __restrict__ pw1bT, const float* __restrict__ pwvaT,
    const int* __restrict__ rank,
    float* __restrict__ F1, float* __restrict__ F2, float* __restrict__ FV)
{
    int t = threadIdx.x;
    int lane = t & 63;
    int wave = t >> 6;
    int pt0 = blockIdx.x * 64 + wave * 16;
    int b   = __builtin_amdgcn_readfirstlane(pt0 >> 13);
    int n0  = __builtin_amdgcn_readfirstlane(pt0 & 8191);
    const float* fb = feats + (unsigned)b * CC * NN;
    float accA[16], accB[16], accV[16];
    float bb1 = b1[lane], bbv = bv[lane];
#pragma unroll
    for (int p = 0; p < 16; p++) { accA[p] = bb1; accB[p] = 0.f; accV[p] = bbv; }
    for (int c = 0; c < 64; c++) {
        float wA = pw1aT[c * 64 + lane];
        float wB = pw1bT[c * 64 + lane];
        float wV = pwvaT[c * 64 + lane];
        const float* fr = fb + (unsigned)c * NN + n0;
#pragma unroll
        for (int p = 0; p < 16; p++) {
            float f = fr[p];
            accA[p] = fmaf(wA, f, accA[p]);
            accB[p] = fmaf(wB, f, accB[p]);
            accV[p] = fmaf(wV, f, accV[p]);
        }
    }
#pragma unroll
    for (int p = 0; p < 16; p++) {
        unsigned dst = ((unsigned)b << 13) + (unsigned)rank[pt0 + p];  // wave-uniform
        F1[dst * 64u + lane] = accA[p];
        F2[dst * 64u + lane] = accB[p];
        FV[dst * 64u + lane] = accV[p];
    }
}

// Fused KNN + fp64 refine + h/v BN-stats. ONE query per wave, XCD-swizzled.
// Round-5 (resubmit; prior bench was an infra failure): per-wave logic
// byte-identical to round-3 (proven 107us); ONLY the launch geometry changes:
// 256-thread blocks (4 waves / 4 queries) instead of 128-thread (2 waves).
// Rationale: k_knn occupancy plateaued at ~50% across r0-r4 regardless of
// VGPR -> consistent with an ~8 workgroup/CU slot cap (8 x 2 waves = 16/32).
// 4-wave blocks lift the cap to 32 waves/CU, doubling TLP for this
// latency-bound kernel.
__global__ __launch_bounds__(256) void k_knn(
    const float4* __restrict__ sx4, const int* __restrict__ sid,
    const float4* __restrict__ bbmin, const float4* __restrict__ bbmax,
    const float* __restrict__ F1, const float* __restrict__ F2, const float* __restrict__ FV,
    const float* __restrict__ relw,
    int* __restrict__ idx, float* __restrict__ ph2)
{
    __shared__ int cand[4][CAP];
    int lane = threadIdx.x & 63;
    int wl = threadIdx.x >> 6;
    int bx = blockIdx.x;                       // 8192 blocks
    int vb = (bx & 7) * 1024 + (bx >> 3);      // XCD-aware swizzle (bijective)
    int gq = vb * 4 + wl;
    int b = __builtin_amdgcn_readfirstlane(gq >> 13);
    int qs = gq & 8191;
    const float4* sb = sx4 + ((unsigned)b << 13);
    const int* ib = sid + ((unsigned)b << 13);
    float4 me = sb[qs];                       // wave-uniform
    const float INF = 3.402823466e38f;
    int* wc = cand[wl];

    // early-issue long-latency loads (used only after the sort chains)
    float rw0 = relw[0 * 64 + lane], rw1 = relw[1 * 64 + lane], rw2 = relw[2 * 64 + lane];
    float rw3 = relw[3 * 64 + lane], rw4 = relw[4 * 64 + lane], rw5 = relw[5 * 64 + lane];
    float F1v = F1[(unsigned)gq * 64u + lane];
    float md0 = mind2(me, bbmin[b * CHN + lane], bbmax[b * CHN + lane]);
    float md1 = mind2(me, bbmin[b * CHN + 64 + lane], bbmax[b * CHN + 64 + lane]);

    // phase 1: positional window; values-only bitonic -> tau16
    int ws0 = qs - 32; ws0 = ws0 < 0 ? 0 : (ws0 > (NN - 64) ? (NN - 64) : ws0);
    float4 cp = sb[(unsigned)(ws0 + lane)];
    float d = distf(me, cp.x, cp.y, cp.z, cp.w);
    float s = d;
#pragma unroll
    for (int k2 = 2; k2 <= 64; k2 <<= 1) {
#pragma unroll
        for (int j2 = k2 >> 1; j2 >= 1; j2 >>= 1) {
            float o = __shfl_xor(s, j2, 64);
            bool wantMin = (((lane & j2) == 0) == ((lane & k2) == 0));
            s = wantMin ? fminf(s, o) : fmaxf(s, o);
        }
    }
    float tau = __int_as_float(__builtin_amdgcn_readlane(__float_as_int(s), 15));
    float tauA = tau * 1.0001f + 1e-5f;

    int cnt;
    {
        bool hit = (d <= tauA);
        unsigned long long hm = __ballot(hit);
        if (hit) wc[mbcnt64(hm)] = ws0 + lane;     // unsorted seed: same SET
        cnt = __popcll(hm);

        unsigned long long bm0 = __ballot(md0 <= tauA);
        unsigned long long bm1 = __ballot(md1 <= tauA);

        int c0 = -1;
        if (bm0)      { c0 = __builtin_ctzll(bm0); bm0 &= bm0 - 1; }
        else if (bm1) { c0 = 64 + __builtin_ctzll(bm1); bm1 &= bm1 - 1; }
        float4 p0 = make_float4(0.f, 0.f, 0.f, 0.f);
        if (c0 >= 0) p0 = sb[(unsigned)(c0 * CHSZ + lane)];
        while (c0 >= 0) {
            int c1 = -1;
            if (bm0)      { c1 = __builtin_ctzll(bm0); bm0 &= bm0 - 1; }
            else if (bm1) { c1 = 64 + __builtin_ctzll(bm1); bm1 &= bm1 - 1; }
            float4 p1 = p0;
            if (c1 >= 0) p1 = sb[(unsigned)(c1 * CHSZ + lane)];
            int pos = c0 * CHSZ + lane;
            float dd = distf(me, p0.x, p0.y, p0.z, p0.w);
            bool inwin = (pos >= ws0) && (pos < ws0 + 64);
            bool hit2 = (dd <= tauA) && !inwin;
            unsigned long long m2 = __ballot(hit2);
            if (hit2) {
                int slot = cnt + mbcnt64(m2);
                if (slot < CAP) wc[slot] = pos;
            }
            cnt += __popcll(m2);
            c0 = c1; p0 = p1;
        }
    }

    if (cnt > CAP) {
        // rare fallback: re-sort window WITH ids, verified sorted-insert top-32
        float fd = d; int cid = ws0 + lane;
#pragma unroll
        for (int k2 = 2; k2 <= 64; k2 <<= 1) {
#pragma unroll
            for (int j2 = k2 >> 1; j2 >= 1; j2 >>= 1) {
                float od = __shfl_xor(fd, j2, 64);
                int   oi = __shfl_xor(cid, j2, 64);
                bool wantMin = (((lane & j2) == 0) == ((lane & k2) == 0));
                bool to = wantMin ? (od < fd) : (od > fd);
                fd = to ? od : fd; cid = to ? oi : cid;
            }
        }
        bool lt32 = (lane < 32);
        float val = lt32 ? fd : INF;
        int vid = cid;
        float tau2 = __int_as_float(__builtin_amdgcn_readlane(__float_as_int(val), 31));
        float t2A = tau2 * 1.0001f + 1e-5f;
        unsigned long long fb0 = __ballot(md0 <= t2A);
        unsigned long long fb1 = __ballot(md1 <= t2A);
        while (fb0 | fb1) {
            int c;
            if (fb0) { c = __builtin_ctzll(fb0); fb0 &= fb0 - 1; }
            else     { c = 64 + __builtin_ctzll(fb1); fb1 &= fb1 - 1; }
            int pos = c * CHSZ + lane;
            float4 p = sb[(unsigned)pos];
            float dd = distf(me, p.x, p.y, p.z, p.w);
            bool inwin = (pos >= ws0) && (pos < ws0 + 64);
            dd = inwin ? INF : dd;
            unsigned long long m = __ballot(dd < tau2);
            while (m) {
                int hl = __builtin_ctzll(m); m &= m - 1;
                float dn = __int_as_float(
                    __builtin_amdgcn_readlane(__float_as_int(dd), hl));
                int jn = c * CHSZ + hl;
                unsigned long long bl = __ballot(val < dn);
                int pos2 = __popcll(bl);
                float sv = __shfl_up(val, 1, 64);
                int   sj = __shfl_up(vid, 1, 64);
                float nv = (lane > pos2) ? sv : val; nv = (lane == pos2) ? dn : nv;
                int   nj = (lane > pos2) ? sj : vid; nj = (lane == pos2) ? jn : nj;
                val = lt32 ? nv : val;
                vid = lt32 ? nj : vid;
                tau2 = __int_as_float(__builtin_amdgcn_readlane(__float_as_int(val), 31));
            }
        }
        if (lt32) wc[lane] = vid;
        cnt = 32;
    }

    // fp64 refine as single u64 key partial top-16 selection (16 stages)
    unsigned long long key;
    {
        double mx = (double)me.x, my = (double)me.y, mz = (double)me.z;
        double msq = (mx * mx + my * my) + mz * mz;
        if (lane < cnt) {
            int j = wc[lane];
            float4 cj = sb[(unsigned)j];
            double jx = (double)cj.x, jy = (double)cj.y, jz = (double)cj.z;
            double dot = (mx * jx + my * jy) + mz * jz;
            double sqj = (jx * jx + jy * jy) + jz * jz;
            double dd = (-2.0 * dot + msq) + sqj;
            dd = fmax(dd, 0.0);               // guard sign bit for u64 ordering
            unsigned long long pay = (unsigned long long)(unsigned int)((ib[j] << 13) | j);
            key = ((unsigned long long)__double_as_longlong(dd) & ~0x3FFFFFFULL) | pay;
        } else {
            key = (0x7FFULL << 52) | (unsigned int)lane;   // > any valid key, unique
        }
    }

#define CE(MASK, WMIN) do {                                                   \
        unsigned long long ok = shflx_u64(key, (MASK));                       \
        bool ol = ok < key;                                                   \
        bool tk = (WMIN) ? ol : !ol;                                          \
        key = tk ? ok : key;                                                  \
    } while (0)

    // stage A: sort 16-lane groups, alternating direction (10 exchanges)
#pragma unroll
    for (int k2 = 2; k2 <= 16; k2 <<= 1) {
#pragma unroll
        for (int j2 = k2 >> 1; j2 >= 1; j2 >>= 1) {
            bool wantMin = (((lane & j2) == 0) == ((lane & k2) == 0));
            CE(j2, wantMin);
        }
    }
    // stage B: bitonic halving: lanes 0..15 / 32..47 keep min-16
    CE(16, ((lane & 16) == 0));
    // stage C: sort the two bitonic 16-seqs ascending (4 exchanges)
#pragma unroll
    for (int j2 = 8; j2 >= 1; j2 >>= 1)
        CE(j2, ((lane & j2) == 0));
    // stage D: cross-merge sorted 16-sets: lane L (0..15) pairs with 47-L
    CE(47, true);
#undef CE

    int jw = (int)(key & 8191);               // sorted-space neighbor id (lanes 0..15)
    if (lane < 16) idx[(unsigned)gq * 16u + lane] = jw;

    // ---- fused h/v BN stats for this query's 16 neighbors (4-wide batches) ----
    unsigned gb = (unsigned)b << 13;
    float sh = 0.f, sh2 = 0.f, sv = 0.f, sv2 = 0.f;
#pragma unroll
    for (int kb = 0; kb < 4; kb++) {
        float4 cjA[4]; float f2A[4], fvA[4];
#pragma unroll
        for (int jj = 0; jj < 4; jj++) {
            int g = __builtin_amdgcn_readlane(jw, kb * 4 + jj);   // k-th neighbor id
            cjA[jj] = sb[(unsigned)g];
            unsigned go = (gb + (unsigned)g) * 64u + lane;
            f2A[jj] = F2[go];
            fvA[jj] = FV[go];
        }
#pragma unroll
        for (int jj = 0; jj < 4; jj++) {
            float rx = cjA[jj].x - me.x, ry = cjA[jj].y - me.y, rz = cjA[jj].z - me.z;
            float h = F1v + f2A[jj];
            h = fmaf(rw0, rx, h); h = fmaf(rw1, ry, h); h = fmaf(rw2, rz, h);
            float v = fvA[jj];
            v = fmaf(rw3, rx, v); v = fmaf(rw4, ry, v); v = fmaf(rw5, rz, v);
            sh += h; sh2 = fmaf(h, h, sh2);
            sv += v; sv2 = fmaf(v, v, sv2);
        }
    }
    float* bucket = ph2 + (unsigned)(bx & 255) * 256u;
    atomicAdd(&bucket[lane], sh);
    atomicAdd(&bucket[64 + lane], sh2);
    atomicAdd(&bucket[128 + lane], sv);
    atomicAdd(&bucket[192 + lane], sv2);
}

// Reduce PH2[256][256] -> stats[0..255]. 8 blocks; 8 atomics/addr.
__global__ __launch_bounds__(256) void k_red1(
    const float* __restrict__ ph2, float* __restrict__ stats)
{
    int t = threadIdx.x, p = blockIdx.x;
    float acc = 0.f;
    for (int i = 0; i < 32; i++)
        acc += ph2[(unsigned)(p * 32 + i) * 256u + t];
    atomicAdd(&stats[t], acc);
}

// Attention + fused Wo matvec + o-stats. SORTED space, XCD-swizzled.
__global__ __launch_bounds__(256) void k_attn(
    const float4* __restrict__ sx4, const int* __restrict__ sid,
    const int* __restrict__ idx,
    const float* __restrict__ F1, const float* __restrict__ F2, const float* __restrict__ FV,
    const float* __restrict__ relw, const float* __restrict__ stats,
    const float* __restrict__ g1, const float* __restrict__ be1,
    const float* __restrict__ W2, const float* __restrict__ b2,
    const float* __restrict__ gv, const float* __restrict__ bev,
    const float* __restrict__ pwoT, const float* __restrict__ bo,
    float* __restrict__ opre, float* __restrict__ po2)
{
    __shared__ float lds_out[4][64];
    int t = threadIdx.x;
    int lane = t & 63;
    int wl = t >> 6;
    int bx = blockIdx.x;                      // 8192 blocks
    int vb = (bx & 7) * 1024 + (bx >> 3);     // XCD-aware swizzle
    int gq = vb * 4 + wl;                     // sorted-global query
    const float invM = 1.f / 524288.f;
    float hm = stats[lane] * invM, hq = stats[64 + lane] * invM;
    float s1 = g1[lane] * rsqrtf(hq - hm * hm + EPSBN);
    float t1 = be1[lane] - s1 * hm;
    float vm = stats[128 + lane] * invM, vq = stats[192 + lane] * invM;
    float sv = gv[lane] * rsqrtf(vq - vm * vm + EPSBN);
    float tv = bev[lane] - sv * vm;
    float rw0 = relw[0 * 64 + lane], rw1 = relw[1 * 64 + lane], rw2 = relw[2 * 64 + lane];
    float rw3 = relw[3 * 64 + lane], rw4 = relw[4 * 64 + lane], rw5 = relw[5 * 64 + lane];
    float w2v = W2[lane];
    float b2v = b2[0];
    float bov = bo[lane];

    int b = __builtin_amdgcn_readfirstlane(gq >> 13);
    const float4* sb = sx4 + ((unsigned)b << 13);
    float4 me = sb[(unsigned)(gq & 8191)];
    float F1v = F1[(unsigned)gq * 64u + lane];
    unsigned orig = ((unsigned)b << 13) + (unsigned)sid[gq];   // wave-uniform
    const int* ip = idx + (unsigned)gq * 16u;
    unsigned gb = (unsigned)b << 13;
    float ek[16], vk[16];
#pragma unroll
    for (int kb = 0; kb < 2; kb++) {
        float4 cjA[8]; float f2A[8], fvA[8];
#pragma unroll
        for (int jj = 0; jj < 8; jj++) {
            int gl = ip[kb * 8 + jj];
            cjA[jj] = sb[(unsigned)gl];
            unsigned go = (gb + (unsigned)gl) * 64u + lane;
            f2A[jj] = F2[go];
            fvA[jj] = FV[go];
        }
#pragma unroll
        for (int jj = 0; jj < 8; jj++) {
            int k = kb * 8 + jj;
            float rx = cjA[jj].x - me.x, ry = cjA[jj].y - me.y, rz = cjA[jj].z - me.z;
            float h = F1v + f2A[jj];
            h = fmaf(rw0, rx, h); h = fmaf(rw1, ry, h); h = fmaf(rw2, rz, h);
            float a = fmaxf(fmaf(s1, h, t1), 0.f);
            float v = fvA[jj];
            v = fmaf(rw3, rx, v); v = fmaf(rw4, ry, v); v = fmaf(rw5, rz, v);
            vk[k] = fmaxf(fmaf(sv, v, tv), 0.f);
            float lg = w2v * a;
#pragma unroll
            for (int off = 32; off >= 1; off >>= 1) lg += __shfl_xor(lg, off, 64);
            ek[k] = lg + b2v;
        }
    }
    float mx = ek[0];
#pragma unroll
    for (int k = 1; k < 16; k++) mx = fmaxf(mx, ek[k]);
    float ssum = 0.f;
#pragma unroll
    for (int k = 0; k < 16; k++) { float e = __expf(ek[k] - mx); ek[k] = e; ssum += e; }
    float acc = 0.f;
#pragma unroll
    for (int k = 0; k < 16; k++) acc = fmaf(ek[k], vk[k], acc);
    float ov = acc / ssum;

    // fused Wo matvec: wave-local LDS row; 4 accumulators break the 64-deep
    // serial fmaf chain
    lds_out[wl][lane] = ov;
    float op0 = bov, op1 = 0.f, op2 = 0.f, op3 = 0.f;
#pragma unroll
    for (int c = 0; c < 64; c += 4) {
        op0 = fmaf(pwoT[(c + 0) * 64 + lane], lds_out[wl][c + 0], op0);
        op1 = fmaf(pwoT[(c + 1) * 64 + lane], lds_out[wl][c + 1], op1);
        op2 = fmaf(pwoT[(c + 2) * 64 + lane], lds_out[wl][c + 2], op2);
        op3 = fmaf(pwoT[(c + 3) * 64 + lane], lds_out[wl][c + 3], op3);
    }
    float op = (op0 + op1) + (op2 + op3);
    opre[orig * 64u + lane] = op;

    float* bucket = po2 + (unsigned)(bx & 255) * 128u;
    atomicAdd(&bucket[lane], op);
    atomicAdd(&bucket[64 + lane], op * op);
}

// Reduce PO2[256][128] -> stats[256..383]. 8 blocks; 8 atomics/addr.
__global__ __launch_bounds__(256) void k_red2(
    const float* __restrict__ po2, float* __restrict__ stats)
{
    int t = threadIdx.x, p = blockIdx.x;
    if (t < 128) {
        float acc = 0.f;
        for (int i = 0; i < 32; i++)
            acc += po2[(unsigned)(p * 32 + i) * 128u + t];
        atomicAdd(&stats[256 + t], acc);
    }
}

// Final: BN(o)+relu + residual feats, transpose [B,N,C]->[B,C,N]
__global__ __launch_bounds__(256) void k_final(
    const float* __restrict__ opre, const float* __restrict__ stats,
    const float* __restrict__ go, const float* __restrict__ beo,
    const float* __restrict__ feats, float* __restrict__ out)
{
    __shared__ float tile[64][65];
    int t = threadIdx.x;
    int blk = blockIdx.x;
    int b = blk >> 7, n0 = (blk & 127) << 6;
#pragma unroll
    for (int i = 0; i < 16; i++) {
        int e = t + i * 256;
        int r = e >> 6, c = e & 63;
        tile[r][c] = opre[(unsigned)((b << 13) + n0 + r) * 64u + c];
    }
    __syncthreads();
    const float invM = 1.f / 32768.f;
    int lane = t & 63, wv = t >> 6;
#pragma unroll
    for (int i = 0; i < 16; i++) {
        int c = wv * 16 + i;
        float om = stats[256 + c] * invM, oq = stats[320 + c] * invM;
        float so = go[c] * rsqrtf(oq - om * om + EPSBN);
        float to = beo[c] - so * om;
        float val = fmaxf(fmaf(so, tile[lane][c], to), 0.f);
        unsigned oix = ((unsigned)b * 64 + c) * NN + n0 + lane;
        out[oix] = val + feats[oix];
    }
}

extern "C" void kernel_launch(void* const* d_in, const int* in_sizes, int n_in,
                              void* d_out, int out_size, void* d_ws, size_t ws_size,
                              hipStream_t stream)
{
    const float* xyz  = (const float*)d_in[0];
    const float* feats= (const float*)d_in[1];
    const float* W1   = (const float*)d_in[2];
    const float* b1   = (const float*)d_in[3];
    const float* g1   = (const float*)d_in[4];
    const float* be1  = (const float*)d_in[5];
    const float* W2   = (const float*)d_in[6];
    const float* b2   = (const float*)d_in[7];
    const float* Wv   = (const float*)d_in[8];
    const float* bv   = (const float*)d_in[9];
    const float* gv   = (const float*)d_in[10];
    const float* bev  = (const float*)d_in[11];
    const float* Wo   = (const float*)d_in[12];
    const float* bo   = (const float*)d_in[13];
    const float* go   = (const float*)d_in[14];
    const float* beo  = (const float*)d_in[15];

    float* ws = (float*)d_ws;
    float* xyzw  = ws + OFF_XYZW;
    float* pw1aT = ws + OFF_PW1AT;
    float* pw1bT = ws + OFF_PW1BT;
    float* pwvaT = ws + OFF_PWVAT;
    float* pwoT  = ws + OFF_PWOT;
    float* relw  = ws + OFF_RELW;
    float* stats = ws + OFF_STATS;
    int*   idx   = (int*)(ws + OFF_IDX);
    float* opre  = ws + OFF_OPRE;
    float4* sx4  = (float4*)(ws + OFF_SX4);
    int*   sid   = (int*)(ws + OFF_SID);
    int*   hist  = (int*)(ws + OFF_HIST);
    float4* bbmn = (float4*)(ws + OFF_BB);
    float4* bbmx = (float4*)(ws + OFF_BB + 2048);
    int*   rank  = (int*)(ws + OFF_RANK);
    float* ph2   = ws + OFF_PH;
    float* po2   = ws + OFF_PO;
    float* F1    = ws + OFF_F1;
    float* F2    = ws + OFF_F2;
    float* FV    = ws + OFF_FV;

    hipMemsetAsync(hist, 0, BB * NCELL * sizeof(int), stream);
    hipMemsetAsync(ph2, 0, (65536 + 32768) * sizeof(float), stream);  // PH2+PO2 contiguous
    k_prep<<<129, 256, 0, stream>>>(xyz, W1, Wv, Wo, xyzw, hist,
                                    pw1aT, pw1bT, pwvaT, pwoT, relw, stats);
    k_scan<<<4, 256, 0, stream>>>(hist);
    k_scatter<<<128, 256, 0, stream>>>((const float4*)xyzw, hist, sx4, sid, rank);
    k_bbox<<<128, 256, 0, stream>>>((const float4*)sx4, bbmn, bbmx);
    k_F<<<512, 256, 0, stream>>>(feats, b1, bv, pw1aT, pw1bT, pwvaT, rank, F1, F2, FV);
    k_knn<<<NPTS / 4, 256, 0, stream>>>((const float4*)sx4, sid, bbmn, bbmx,
                                        F1, F2, FV, relw, idx, ph2);
    k_red1<<<8, 256, 0, stream>>>(ph2, stats);
    k_attn<<<8192, 256, 0, stream>>>((const float4*)sx4, sid, idx, F1, F2, FV, relw, stats,
                                     g1, be1, W2, b2, gv, bev, pwoT, bo, opre, po2);
    k_red2<<<8, 256, 0, stream>>>(po2, stats);
    k_final<<<512, 256, 0, stream>>>(opre, stats, go, beo, feats, (float*)d_out);
}

// Round 7
// 300.467 us; speedup vs baseline: 1.2363x; 1.0340x over previous
//
#include <hip/hip_runtime.h>
#include <math.h>

// Problem constants
#define BB 4
#define NN 8192
#define CC 64
#define KK 16
#define HH 64
#define NPTS (BB*NN)   // 32768
#define EPSBN 1e-5f
#define CAP 64         // candidate buffer per query (fp64 refine picks 16)
#define NCELL 4096     // 16^3 Morton cells
#define CHN 128        // chunks per batch
#define CHSZ 64        // points per chunk

// ---------------- ws layout (float offsets) ----------------
#define OFF_XYZW  0
#define OFF_PW1AT 131072
#define OFF_PW1BT 135168
#define OFF_PWVAT 139264
#define OFF_PWOT  143360
#define OFF_RELW  147456
#define OFF_STATS 147840
#define OFF_IDX   148224      // idx: 32768*16 ints (SORTED-space neighbor ids)
#define OFF_OPRE  672512      // [32768][64] o_pre, ORIGINAL layout (old OUTV region)
#define OFF_SX4   2769664     // sorted xyzw [4][8192] float4
#define OFF_SID   2900736     // sorted->orig ids [4][8192] int
#define OFF_HIST  2933504     // [4][4096] int
#define OFF_RANK  2950912     // orig->sorted rank [4][8192] int
#define OFF_PH    2983680     // PH2 [256][256] h/v-stat buckets
#define OFF_PO    3049216     // PO2 [256][128] o-stat buckets
#define OFF_BB    3606272     // bbmin[512] f4 (2048) + bbmax[512] f4 (2048)
#define OFF_F1    4866816     // SORTED layout
#define OFF_F2    6963968     // SORTED layout
#define OFF_FV    9061120     // SORTED layout

__device__ __forceinline__ int morton_cell(float x, float y, float z) {
    int cx = (int)floorf((x + 4.f) * 2.f);
    int cy = (int)floorf((y + 4.f) * 2.f);
    int cz = (int)floorf((z + 4.f) * 2.f);
    cx = cx < 0 ? 0 : (cx > 15 ? 15 : cx);
    cy = cy < 0 ? 0 : (cy > 15 ? 15 : cy);
    cz = cz < 0 ? 0 : (cz > 15 ? 15 : cz);
    int ex = (cx & 1) | ((cx & 2) << 2) | ((cx & 4) << 4) | ((cx & 8) << 6);
    int ey = (cy & 1) | ((cy & 2) << 2) | ((cy & 4) << 4) | ((cy & 8) << 6);
    int ez = (cz & 1) | ((cz & 2) << 2) | ((cz & 4) << 4) | ((cz & 8) << 6);
    return ex | (ey << 1) | (ez << 2);
}

__device__ __forceinline__ float distf(float4 me, float jx, float jy, float jz, float jw) {
    float dot = fmaf(me.z, jz, fmaf(me.y, jy, me.x * jx));
    return fmaf(-2.f, dot, me.w) + jw;
}

__device__ __forceinline__ float mind2(float4 me, float4 bmin, float4 bmax) {
    float dx = fmaxf(fmaxf(bmin.x - me.x, me.x - bmax.x), 0.f);
    float dy = fmaxf(fmaxf(bmin.y - me.y, me.y - bmax.y), 0.f);
    float dz = fmaxf(fmaxf(bmin.z - me.z, me.z - bmax.z), 0.f);
    return fmaf(dx, dx, fmaf(dy, dy, dz * dz));
}

__device__ __forceinline__ int mbcnt64(unsigned long long m) {
    return __builtin_amdgcn_mbcnt_hi((unsigned int)(m >> 32),
           __builtin_amdgcn_mbcnt_lo((unsigned int)m, 0));
}

__device__ __forceinline__ unsigned long long shflx_u64(unsigned long long v, int m) {
    int lo = __shfl_xor((int)(unsigned int)v, m, 64);
    int hi = __shfl_xor((int)(unsigned int)(v >> 32), m, 64);
    return ((unsigned long long)(unsigned int)hi << 32) | (unsigned int)lo;
}

__global__ __launch_bounds__(256) void k_prep(
    const float* __restrict__ xyz, const float* __restrict__ W1,
    const float* __restrict__ Wv, const float* __restrict__ Wo,
    float* __restrict__ xyzw, int* __restrict__ hist,
    float* __restrict__ pw1aT, float* __restrict__ pw1bT,
    float* __restrict__ pwvaT, float* __restrict__ pwoT, float* __restrict__ relw,
    float* __restrict__ stats)
{
    int t = threadIdx.x;
    int bid = blockIdx.x;
    if (bid < 128) {
        int pt = bid * 256 + t;
        int b = pt >> 13, n = pt & 8191;
        const float* xb = xyz + (unsigned)b * 3 * NN;
        float x = xb[n], y = xb[NN + n], z = xb[2 * NN + n];
        float sq = __fadd_rn(__fadd_rn(__fmul_rn(x, x), __fmul_rn(y, y)), __fmul_rn(z, z));
        ((float4*)xyzw)[pt] = make_float4(x, y, z, sq);
        atomicAdd(&hist[b * NCELL + morton_cell(x, y, z)], 1);
    } else {
        for (int e = t; e < 4096; e += 256) {
            int c = e >> 6, o = e & 63;
            pw1aT[e] = W1[o * 131 + c];
            pw1bT[e] = W1[o * 131 + 64 + c];
            pwvaT[e] = Wv[o * 67 + c];
            pwoT[e]  = Wo[o * 64 + c];
        }
        for (int e = t; e < 384; e += 256) {
            int d = e >> 6, o = e & 63;
            relw[e] = (d < 3) ? W1[o * 131 + 128 + d] : Wv[o * 67 + 64 + (d - 3)];
            stats[e] = 0.0f;
        }
    }
}

// Exclusive scan of per-batch 4096-bin histogram (in place), one block per batch.
__global__ __launch_bounds__(256) void k_scan(int* __restrict__ hist) {
    __shared__ int part[256];
    int b = blockIdx.x, t = threadIdx.x;
    int* h = hist + b * NCELL;
    int loc[16]; int s = 0;
#pragma unroll
    for (int i = 0; i < 16; i++) { loc[i] = h[t * 16 + i]; s += loc[i]; }
    part[t] = s;
    __syncthreads();
    for (int off = 1; off < 256; off <<= 1) {
        int v = (t >= off) ? part[t - off] : 0;
        __syncthreads();
        part[t] += v;
        __syncthreads();
    }
    int run = (t > 0) ? part[t - 1] : 0;
#pragma unroll
    for (int i = 0; i < 16; i++) { int c = loc[i]; h[t * 16 + i] = run; run += c; }
}

__global__ __launch_bounds__(256) void k_scatter(
    const float4* __restrict__ xyzw, int* __restrict__ off,
    float4* __restrict__ sx4, int* __restrict__ sid, int* __restrict__ rank)
{
    int pt = blockIdx.x * 256 + threadIdx.x;
    int b = pt >> 13, n = pt & 8191;
    float4 p = xyzw[pt];
    int cell = morton_cell(p.x, p.y, p.z);
    int dst = atomicAdd(&off[b * NCELL + cell], 1);
    sx4[(b << 13) + dst] = p;
    sid[(b << 13) + dst] = n;
    rank[pt] = dst;
}

// Per-chunk bbox over 64 sorted points. One wave per chunk; 512 chunks total.
__global__ __launch_bounds__(256) void k_bbox(
    const float4* __restrict__ sx4, float4* __restrict__ bbmin, float4* __restrict__ bbmax)
{
    int t = threadIdx.x, lane = t & 63, wl = t >> 6;
    int ch = blockIdx.x * 4 + wl;             // 0..511
    float4 p = sx4[ch * CHSZ + lane];
    float mnx = p.x, mny = p.y, mnz = p.z, mxx = p.x, mxy = p.y, mxz = p.z;
#pragma unroll
    for (int o = 32; o >= 1; o >>= 1) {
        mnx = fminf(mnx, __shfl_xor(mnx, o, 64)); mxx = fmaxf(mxx, __shfl_xor(mxx, o, 64));
        mny = fminf(mny, __shfl_xor(mny, o, 64)); mxy = fmaxf(mxy, __shfl_xor(mxy, o, 64));
        mnz = fminf(mnz, __shfl_xor(mnz, o, 64)); mxz = fmaxf(mxz, __shfl_xor(mxz, o, 64));
    }
    if (lane == 0) {
        bbmin[ch] = make_float4(mnx, mny, mnz, 0.f);
        bbmax[ch] = make_float4(mxx, mxy, mxz, 0.f);
    }
}

// Per-point GEMVs, output scattered to SORTED layout via rank.
__global__ __launch_bounds__(256) void k_F(
    const float* __restrict__ feats, const float* __restrict__ b1, const float* __restrict__ bv,
    const float* __restrict__ pw1aT, const float* __restrict__ pw1bT, const float* __restrict__ pwvaT,
    const int* __restrict__ rank,
    float* __restrict__ F1, float* __restrict__ F2, float* __restrict__ FV)
{
    int t = threadIdx.x;
    int lane = t & 63;
    int wave = t >> 6;
    int pt0 = blockIdx.x * 64 + wave * 16;
    int b   = __builtin_amdgcn_readfirstlane(pt0 >> 13);
    int n0  = __builtin_amdgcn_readfirstlane(pt0 & 8191);
    const float* fb = feats + (unsigned)b * CC * NN;
    float accA[16], accB[16], accV[16];
    float bb1 = b1[lane], bbv = bv[lane];
#pragma unroll
    for (int p = 0; p < 16; p++) { accA[p] = bb1; accB[p] = 0.f; accV[p] = bbv; }
    for (int c = 0; c < 64; c++) {
        float wA = pw1aT[c * 64 + lane];
        float wB = pw1bT[c * 64 + lane];
        float wV = pwvaT[c * 64 + lane];
        const float* fr = fb + (unsigned)c * NN + n0;
#pragma unroll
        for (int p = 0; p < 16; p++) {
            float f = fr[p];
            accA[p] = fmaf(wA, f, accA[p]);
            accB[p] = fmaf(wB, f, accB[p]);
            accV[p] = fmaf(wV, f, accV[p]);
        }
    }
#pragma unroll
    for (int p = 0; p < 16; p++) {
        unsigned dst = ((unsigned)b << 13) + (unsigned)rank[pt0 + p];  // wave-uniform
        F1[dst * 64u + lane] = accA[p];
        F2[dst * 64u + lane] = accB[p];
        FV[dst * 64u + lane] = accV[p];
    }
}

// Fused KNN + fp64 refine + h/v BN-stats. ONE query per wave, XCD-swizzled.
// Round-7: exact revert to the round-3 kernel (proven 107us; r6's 4-wave
// blocks regressed to 110 and falsified the slot-cap theory).
__global__ __launch_bounds__(128) void k_knn(
    const float4* __restrict__ sx4, const int* __restrict__ sid,
    const float4* __restrict__ bbmin, const float4* __restrict__ bbmax,
    const float* __restrict__ F1, const float* __restrict__ F2, const float* __restrict__ FV,
    const float* __restrict__ relw,
    int* __restrict__ idx, float* __restrict__ ph2)
{
    __shared__ int cand[2][CAP];
    int lane = threadIdx.x & 63;
    int wl = threadIdx.x >> 6;
    int bx = blockIdx.x;                       // 16384 blocks
    int vb = (bx & 7) * 2048 + (bx >> 3);      // XCD-aware swizzle (bijective)
    int gq = vb * 2 + wl;
    int b = __builtin_amdgcn_readfirstlane(gq >> 13);
    int qs = gq & 8191;
    const float4* sb = sx4 + ((unsigned)b << 13);
    const int* ib = sid + ((unsigned)b << 13);
    float4 me = sb[qs];                       // wave-uniform
    const float INF = 3.402823466e38f;
    int* wc = cand[wl];

    // early-issue long-latency loads (used only after the sort chains)
    float rw0 = relw[0 * 64 + lane], rw1 = relw[1 * 64 + lane], rw2 = relw[2 * 64 + lane];
    float rw3 = relw[3 * 64 + lane], rw4 = relw[4 * 64 + lane], rw5 = relw[5 * 64 + lane];
    float F1v = F1[(unsigned)gq * 64u + lane];
    float md0 = mind2(me, bbmin[b * CHN + lane], bbmax[b * CHN + lane]);
    float md1 = mind2(me, bbmin[b * CHN + 64 + lane], bbmax[b * CHN + 64 + lane]);

    // phase 1: positional window; values-only bitonic -> tau16
    int ws0 = qs - 32; ws0 = ws0 < 0 ? 0 : (ws0 > (NN - 64) ? (NN - 64) : ws0);
    float4 cp = sb[(unsigned)(ws0 + lane)];
    float d = distf(me, cp.x, cp.y, cp.z, cp.w);
    float s = d;
#pragma unroll
    for (int k2 = 2; k2 <= 64; k2 <<= 1) {
#pragma unroll
        for (int j2 = k2 >> 1; j2 >= 1; j2 >>= 1) {
            float o = __shfl_xor(s, j2, 64);
            bool wantMin = (((lane & j2) == 0) == ((lane & k2) == 0));
            s = wantMin ? fminf(s, o) : fmaxf(s, o);
        }
    }
    float tau = __int_as_float(__builtin_amdgcn_readlane(__float_as_int(s), 15));
    float tauA = tau * 1.0001f + 1e-5f;

    int cnt;
    {
        bool hit = (d <= tauA);
        unsigned long long hm = __ballot(hit);
        if (hit) wc[mbcnt64(hm)] = ws0 + lane;     // unsorted seed: same SET
        cnt = __popcll(hm);

        unsigned long long bm0 = __ballot(md0 <= tauA);
        unsigned long long bm1 = __ballot(md1 <= tauA);

        int c0 = -1;
        if (bm0)      { c0 = __builtin_ctzll(bm0); bm0 &= bm0 - 1; }
        else if (bm1) { c0 = 64 + __builtin_ctzll(bm1); bm1 &= bm1 - 1; }
        float4 p0 = make_float4(0.f, 0.f, 0.f, 0.f);
        if (c0 >= 0) p0 = sb[(unsigned)(c0 * CHSZ + lane)];
        while (c0 >= 0) {
            int c1 = -1;
            if (bm0)      { c1 = __builtin_ctzll(bm0); bm0 &= bm0 - 1; }
            else if (bm1) { c1 = 64 + __builtin_ctzll(bm1); bm1 &= bm1 - 1; }
            float4 p1 = p0;
            if (c1 >= 0) p1 = sb[(unsigned)(c1 * CHSZ + lane)];
            int pos = c0 * CHSZ + lane;
            float dd = distf(me, p0.x, p0.y, p0.z, p0.w);
            bool inwin = (pos >= ws0) && (pos < ws0 + 64);
            bool hit2 = (dd <= tauA) && !inwin;
            unsigned long long m2 = __ballot(hit2);
            if (hit2) {
                int slot = cnt + mbcnt64(m2);
                if (slot < CAP) wc[slot] = pos;
            }
            cnt += __popcll(m2);
            c0 = c1; p0 = p1;
        }
    }

    if (cnt > CAP) {
        // rare fallback: re-sort window WITH ids, verified sorted-insert top-32
        float fd = d; int cid = ws0 + lane;
#pragma unroll
        for (int k2 = 2; k2 <= 64; k2 <<= 1) {
#pragma unroll
            for (int j2 = k2 >> 1; j2 >= 1; j2 >>= 1) {
                float od = __shfl_xor(fd, j2, 64);
                int   oi = __shfl_xor(cid, j2, 64);
                bool wantMin = (((lane & j2) == 0) == ((lane & k2) == 0));
                bool to = wantMin ? (od < fd) : (od > fd);
                fd = to ? od : fd; cid = to ? oi : cid;
            }
        }
        bool lt32 = (lane < 32);
        float val = lt32 ? fd : INF;
        int vid = cid;
        float tau2 = __int_as_float(__builtin_amdgcn_readlane(__float_as_int(val), 31));
        float t2A = tau2 * 1.0001f + 1e-5f;
        unsigned long long fb0 = __ballot(md0 <= t2A);
        unsigned long long fb1 = __ballot(md1 <= t2A);
        while (fb0 | fb1) {
            int c;
            if (fb0) { c = __builtin_ctzll(fb0); fb0 &= fb0 - 1; }
            else     { c = 64 + __builtin_ctzll(fb1); fb1 &= fb1 - 1; }
            int pos = c * CHSZ + lane;
            float4 p = sb[(unsigned)pos];
            float dd = distf(me, p.x, p.y, p.z, p.w);
            bool inwin = (pos >= ws0) && (pos < ws0 + 64);
            dd = inwin ? INF : dd;
            unsigned long long m = __ballot(dd < tau2);
            while (m) {
                int hl = __builtin_ctzll(m); m &= m - 1;
                float dn = __int_as_float(
                    __builtin_amdgcn_readlane(__float_as_int(dd), hl));
                int jn = c * CHSZ + hl;
                unsigned long long bl = __ballot(val < dn);
                int pos2 = __popcll(bl);
                float sv = __shfl_up(val, 1, 64);
                int   sj = __shfl_up(vid, 1, 64);
                float nv = (lane > pos2) ? sv : val; nv = (lane == pos2) ? dn : nv;
                int   nj = (lane > pos2) ? sj : vid; nj = (lane == pos2) ? jn : nj;
                val = lt32 ? nv : val;
                vid = lt32 ? nj : vid;
                tau2 = __int_as_float(__builtin_amdgcn_readlane(__float_as_int(val), 31));
            }
        }
        if (lt32) wc[lane] = vid;
        cnt = 32;
    }

    // fp64 refine as single u64 key partial top-16 selection (16 stages)
    unsigned long long key;
    {
        double mx = (double)me.x, my = (double)me.y, mz = (double)me.z;
        double msq = (mx * mx + my * my) + mz * mz;
        if (lane < cnt) {
            int j = wc[lane];
            float4 cj = sb[(unsigned)j];
            double jx = (double)cj.x, jy = (double)cj.y, jz = (double)cj.z;
            double dot = (mx * jx + my * jy) + mz * jz;
            double sqj = (jx * jx + jy * jy) + jz * jz;
            double dd = (-2.0 * dot + msq) + sqj;
            dd = fmax(dd, 0.0);               // guard sign bit for u64 ordering
            unsigned long long pay = (unsigned long long)(unsigned int)((ib[j] << 13) | j);
            key = ((unsigned long long)__double_as_longlong(dd) & ~0x3FFFFFFULL) | pay;
        } else {
            key = (0x7FFULL << 52) | (unsigned int)lane;   // > any valid key, unique
        }
    }

#define CE(MASK, WMIN) do {                                                   \
        unsigned long long ok = shflx_u64(key, (MASK));                       \
        bool ol = ok < key;                                                   \
        bool tk = (WMIN) ? ol : !ol;                                          \
        key = tk ? ok : key;                                                  \
    } while (0)

    // stage A: sort 16-lane groups, alternating direction (10 exchanges)
#pragma unroll
    for (int k2 = 2; k2 <= 16; k2 <<= 1) {
#pragma unroll
        for (int j2 = k2 >> 1; j2 >= 1; j2 >>= 1) {
            bool wantMin = (((lane & j2) == 0) == ((lane & k2) == 0));
            CE(j2, wantMin);
        }
    }
    // stage B: bitonic halving: lanes 0..15 / 32..47 keep min-16
    CE(16, ((lane & 16) == 0));
    // stage C: sort the two bitonic 16-seqs ascending (4 exchanges)
#pragma unroll
    for (int j2 = 8; j2 >= 1; j2 >>= 1)
        CE(j2, ((lane & j2) == 0));
    // stage D: cross-merge sorted 16-sets: lane L (0..15) pairs with 47-L
    CE(47, true);
#undef CE

    int jw = (int)(key & 8191);               // sorted-space neighbor id (lanes 0..15)
    if (lane < 16) idx[(unsigned)gq * 16u + lane] = jw;

    // ---- fused h/v BN stats for this query's 16 neighbors (4-wide batches) ----
    unsigned gb = (unsigned)b << 13;
    float sh = 0.f, sh2 = 0.f, sv = 0.f, sv2 = 0.f;
#pragma unroll
    for (int kb = 0; kb < 4; kb++) {
        float4 cjA[4]; float f2A[4], fvA[4];
#pragma unroll
        for (int jj = 0; jj < 4; jj++) {
            int g = __builtin_amdgcn_readlane(jw, kb * 4 + jj);   // k-th neighbor id
            cjA[jj] = sb[(unsigned)g];
            unsigned go = (gb + (unsigned)g) * 64u + lane;
            f2A[jj] = F2[go];
            fvA[jj] = FV[go];
        }
#pragma unroll
        for (int jj = 0; jj < 4; jj++) {
            float rx = cjA[jj].x - me.x, ry = cjA[jj].y - me.y, rz = cjA[jj].z - me.z;
            float h = F1v + f2A[jj];
            h = fmaf(rw0, rx, h); h = fmaf(rw1, ry, h); h = fmaf(rw2, rz, h);
            float v = fvA[jj];
            v = fmaf(rw3, rx, v); v = fmaf(rw4, ry, v); v = fmaf(rw5, rz, v);
            sh += h; sh2 = fmaf(h, h, sh2);
            sv += v; sv2 = fmaf(v, v, sv2);
        }
    }
    float* bucket = ph2 + (unsigned)(bx & 255) * 256u;
    atomicAdd(&bucket[lane], sh);
    atomicAdd(&bucket[64 + lane], sh2);
    atomicAdd(&bucket[128 + lane], sv);
    atomicAdd(&bucket[192 + lane], sv2);
}

// Reduce PH2[256][256] -> stats[0..255]. 8 blocks; 8 atomics/addr.
__global__ __launch_bounds__(256) void k_red1(
    const float* __restrict__ ph2, float* __restrict__ stats)
{
    int t = threadIdx.x, p = blockIdx.x;
    float acc = 0.f;
    for (int i = 0; i < 32; i++)
        acc += ph2[(unsigned)(p * 32 + i) * 256u + t];
    atomicAdd(&stats[t], acc);
}

// Attention + fused Wo matvec + o-stats. SORTED space, XCD-swizzled.
// Round-7: logit reduction rebuilt as a split-butterfly multi-reduce — all 16
// 64-lane sums in 17 shfls (vs 16 x 6 = 96) with the IDENTICAL binary
// summation tree (stage order 32,16,8,4,2,1; lane pairs with lane^off at each
// stage), so ek is bit-identical. S_k lands on lane 4k; broadcast via
// v_readlane.
__global__ __launch_bounds__(256) void k_attn(
    const float4* __restrict__ sx4, const int* __restrict__ sid,
    const int* __restrict__ idx,
    const float* __restrict__ F1, const float* __restrict__ F2, const float* __restrict__ FV,
    const float* __restrict__ relw, const float* __restrict__ stats,
    const float* __restrict__ g1, const float* __restrict__ be1,
    const float* __restrict__ W2, const float* __restrict__ b2,
    const float* __restrict__ gv, const float* __restrict__ bev,
    const float* __restrict__ pwoT, const float* __restrict__ bo,
    float* __restrict__ opre, float* __restrict__ po2)
{
    __shared__ float lds_out[4][64];
    int t = threadIdx.x;
    int lane = t & 63;
    int wl = t >> 6;
    int bx = blockIdx.x;                      // 8192 blocks
    int vb = (bx & 7) * 1024 + (bx >> 3);     // XCD-aware swizzle
    int gq = vb * 4 + wl;                     // sorted-global query
    const float invM = 1.f / 524288.f;
    float hm = stats[lane] * invM, hq = stats[64 + lane] * invM;
    float s1 = g1[lane] * rsqrtf(hq - hm * hm + EPSBN);
    float t1 = be1[lane] - s1 * hm;
    float vm = stats[128 + lane] * invM, vq = stats[192 + lane] * invM;
    float sv = gv[lane] * rsqrtf(vq - vm * vm + EPSBN);
    float tv = bev[lane] - sv * vm;
    float rw0 = relw[0 * 64 + lane], rw1 = relw[1 * 64 + lane], rw2 = relw[2 * 64 + lane];
    float rw3 = relw[3 * 64 + lane], rw4 = relw[4 * 64 + lane], rw5 = relw[5 * 64 + lane];
    float w2v = W2[lane];
    float b2v = b2[0];
    float bov = bo[lane];

    int b = __builtin_amdgcn_readfirstlane(gq >> 13);
    const float4* sb = sx4 + ((unsigned)b << 13);
    float4 me = sb[(unsigned)(gq & 8191)];
    float F1v = F1[(unsigned)gq * 64u + lane];
    unsigned orig = ((unsigned)b << 13) + (unsigned)sid[gq];   // wave-uniform
    const int* ip = idx + (unsigned)gq * 16u;
    unsigned gb = (unsigned)b << 13;
    float p[16], vk[16];
#pragma unroll
    for (int kb = 0; kb < 2; kb++) {
        float4 cjA[8]; float f2A[8], fvA[8];
#pragma unroll
        for (int jj = 0; jj < 8; jj++) {
            int gl = ip[kb * 8 + jj];
            cjA[jj] = sb[(unsigned)gl];
            unsigned go = (gb + (unsigned)gl) * 64u + lane;
            f2A[jj] = F2[go];
            fvA[jj] = FV[go];
        }
#pragma unroll
        for (int jj = 0; jj < 8; jj++) {
            int k = kb * 8 + jj;
            float rx = cjA[jj].x - me.x, ry = cjA[jj].y - me.y, rz = cjA[jj].z - me.z;
            float h = F1v + f2A[jj];
            h = fmaf(rw0, rx, h); h = fmaf(rw1, ry, h); h = fmaf(rw2, rz, h);
            float a = fmaxf(fmaf(s1, h, t1), 0.f);
            float v = fvA[jj];
            v = fmaf(rw3, rx, v); v = fmaf(rw4, ry, v); v = fmaf(rw5, rz, v);
            vk[k] = fmaxf(fmaf(sv, v, tv), 0.f);
            p[k] = w2v * a;                   // per-lane partial of logit k
        }
    }
    // split-butterfly multi-reduce: same tree as 6-stage xor butterfly per k.
    bool h32 = (lane & 32) != 0;
    float q8[8];
#pragma unroll
    for (int i = 0; i < 8; i++) {
        float send = h32 ? p[i] : p[8 + i];
        float recv = __shfl_xor(send, 32, 64);
        q8[i] = (h32 ? p[8 + i] : p[i]) + recv;
    }
    bool h16 = (lane & 16) != 0;
    float q4[4];
#pragma unroll
    for (int i = 0; i < 4; i++) {
        float send = h16 ? q8[i] : q8[4 + i];
        float recv = __shfl_xor(send, 16, 64);
        q4[i] = (h16 ? q8[4 + i] : q8[i]) + recv;
    }
    bool h8 = (lane & 8) != 0;
    float q2[2];
#pragma unroll
    for (int i = 0; i < 2; i++) {
        float send = h8 ? q4[i] : q4[2 + i];
        float recv = __shfl_xor(send, 8, 64);
        q2[i] = (h8 ? q4[2 + i] : q4[i]) + recv;
    }
    bool h4 = (lane & 4) != 0;
    float tt;
    {
        float send = h4 ? q2[0] : q2[1];
        float recv = __shfl_xor(send, 4, 64);
        tt = (h4 ? q2[1] : q2[0]) + recv;
    }
    tt += __shfl_xor(tt, 2, 64);
    tt += __shfl_xor(tt, 1, 64);
    // S_k lives on lanes where k = (lane>>5&1)*8 + (lane>>4&1)*4 + (lane>>3&1)*2
    //                            + (lane>>2&1)  ==> lane_of_k = 4*k
    float ek[16];
#pragma unroll
    for (int k = 0; k < 16; k++)
        ek[k] = __int_as_float(__builtin_amdgcn_readlane(__float_as_int(tt), 4 * k)) + b2v;

    float mx = ek[0];
#pragma unroll
    for (int k = 1; k < 16; k++) mx = fmaxf(mx, ek[k]);
    float ssum = 0.f;
#pragma unroll
    for (int k = 0; k < 16; k++) { float e = __expf(ek[k] - mx); ek[k] = e; ssum += e; }
    float acc = 0.f;
#pragma unroll
    for (int k = 0; k < 16; k++) acc = fmaf(ek[k], vk[k], acc);
    float ov = acc / ssum;

    // fused Wo matvec: wave-local LDS row; 4 accumulators break the 64-deep
    // serial fmaf chain
    lds_out[wl][lane] = ov;
    float op0 = bov, op1 = 0.f, op2 = 0.f, op3 = 0.f;
#pragma unroll
    for (int c = 0; c < 64; c += 4) {
        op0 = fmaf(pwoT[(c + 0) * 64 + lane], lds_out[wl][c + 0], op0);
        op1 = fmaf(pwoT[(c + 1) * 64 + lane], lds_out[wl][c + 1], op1);
        op2 = fmaf(pwoT[(c + 2) * 64 + lane], lds_out[wl][c + 2], op2);
        op3 = fmaf(pwoT[(c + 3) * 64 + lane], lds_out[wl][c + 3], op3);
    }
    float op = (op0 + op1) + (op2 + op3);
    opre[orig * 64u + lane] = op;

    float* bucket = po2 + (unsigned)(bx & 255) * 128u;
    atomicAdd(&bucket[lane], op);
    atomicAdd(&bucket[64 + lane], op * op);
}

// Reduce PO2[256][128] -> stats[256..383]. 8 blocks; 8 atomics/addr.
__global__ __launch_bounds__(256) void k_red2(
    const float* __restrict__ po2, float* __restrict__ stats)
{
    int t = threadIdx.x, p = blockIdx.x;
    if (t < 128) {
        float acc = 0.f;
        for (int i = 0; i < 32; i++)
            acc += po2[(unsigned)(p * 32 + i) * 128u + t];
        atomicAdd(&stats[256 + t], acc);
    }
}

// Final: BN(o)+relu + residual feats, transpose [B,N,C]->[B,C,N]
__global__ __launch_bounds__(256) void k_final(
    const float* __restrict__ opre, const float* __restrict__ stats,
    const float* __restrict__ go, const float* __restrict__ beo,
    const float* __restrict__ feats, float* __restrict__ out)
{
    __shared__ float tile[64][65];
    int t = threadIdx.x;
    int blk = blockIdx.x;
    int b = blk >> 7, n0 = (blk & 127) << 6;
#pragma unroll
    for (int i = 0; i < 16; i++) {
        int e = t + i * 256;
        int r = e >> 6, c = e & 63;
        tile[r][c] = opre[(unsigned)((b << 13) + n0 + r) * 64u + c];
    }
    __syncthreads();
    const float invM = 1.f / 32768.f;
    int lane = t & 63, wv = t >> 6;
#pragma unroll
    for (int i = 0; i < 16; i++) {
        int c = wv * 16 + i;
        float om = stats[256 + c] * invM, oq = stats[320 + c] * invM;
        float so = go[c] * rsqrtf(oq - om * om + EPSBN);
        float to = beo[c] - so * om;
        float val = fmaxf(fmaf(so, tile[lane][c], to), 0.f);
        unsigned oix = ((unsigned)b * 64 + c) * NN + n0 + lane;
        out[oix] = val + feats[oix];
    }
}

extern "C" void kernel_launch(void* const* d_in, const int* in_sizes, int n_in,
                              void* d_out, int out_size, void* d_ws, size_t ws_size,
                              hipStream_t stream)
{
    const float* xyz  = (const float*)d_in[0];
    const float* feats= (const float*)d_in[1];
    const float* W1   = (const float*)d_in[2];
    const float* b1   = (const float*)d_in[3];
    const float* g1   = (const float*)d_in[4];
    const float* be1  = (const float*)d_in[5];
    const float* W2   = (const float*)d_in[6];
    const float* b2   = (const float*)d_in[7];
    const float* Wv   = (const float*)d_in[8];
    const float* bv   = (const float*)d_in[9];
    const float* gv   = (const float*)d_in[10];
    const float* bev  = (const float*)d_in[11];
    const float* Wo   = (const float*)d_in[12];
    const float* bo   = (const float*)d_in[13];
    const float* go   = (const float*)d_in[14];
    const float* beo  = (const float*)d_in[15];

    float* ws = (float*)d_ws;
    float* xyzw  = ws + OFF_XYZW;
    float* pw1aT = ws + OFF_PW1AT;
    float* pw1bT = ws + OFF_PW1BT;
    float* pwvaT = ws + OFF_PWVAT;
    float* pwoT  = ws + OFF_PWOT;
    float* relw  = ws + OFF_RELW;
    float* stats = ws + OFF_STATS;
    int*   idx   = (int*)(ws + OFF_IDX);
    float* opre  = ws + OFF_OPRE;
    float4* sx4  = (float4*)(ws + OFF_SX4);
    int*   sid   = (int*)(ws + OFF_SID);
    int*   hist  = (int*)(ws + OFF_HIST);
    float4* bbmn = (float4*)(ws + OFF_BB);
    float4* bbmx = (float4*)(ws + OFF_BB + 2048);
    int*   rank  = (int*)(ws + OFF_RANK);
    float* ph2   = ws + OFF_PH;
    float* po2   = ws + OFF_PO;
    float* F1    = ws + OFF_F1;
    float* F2    = ws + OFF_F2;
    float* FV    = ws + OFF_FV;

    hipMemsetAsync(hist, 0, BB * NCELL * sizeof(int), stream);
    hipMemsetAsync(ph2, 0, (65536 + 32768) * sizeof(float), stream);  // PH2+PO2 contiguous
    k_prep<<<129, 256, 0, stream>>>(xyz, W1, Wv, Wo, xyzw, hist,
                                    pw1aT, pw1bT, pwvaT, pwoT, relw, stats);
    k_scan<<<4, 256, 0, stream>>>(hist);
    k_scatter<<<128, 256, 0, stream>>>((const float4*)xyzw, hist, sx4, sid, rank);
    k_bbox<<<128, 256, 0, stream>>>((const float4*)sx4, bbmn, bbmx);
    k_F<<<512, 256, 0, stream>>>(feats, b1, bv, pw1aT, pw1bT, pwvaT, rank, F1, F2, FV);
    k_knn<<<NPTS / 2, 128, 0, stream>>>((const float4*)sx4, sid, bbmn, bbmx,
                                        F1, F2, FV, relw, idx, ph2);
    k_red1<<<8, 256, 0, stream>>>(ph2, stats);
    k_attn<<<8192, 256, 0, stream>>>((const float4*)sx4, sid, idx, F1, F2, FV, relw, stats,
                                     g1, be1, W2, b2, gv, bev, pwoT, bo, opre, po2);
    k_red2<<<8, 256, 0, stream>>>(po2, stats);
    k_final<<<512, 256, 0, stream>>>(opre, stats, go, beo, feats, (float*)d_out);
}

// Round 8
// 299.594 us; speedup vs baseline: 1.2399x; 1.0029x over previous
//
#include <hip/hip_runtime.h>
#include <math.h>

// Problem constants
#define BB 4
#define NN 8192
#define CC 64
#define KK 16
#define HH 64
#define NPTS (BB*NN)   // 32768
#define EPSBN 1e-5f
#define CAP 64         // candidate buffer per query (fp64 refine picks 16)
#define NCELL 4096     // 16^3 Morton cells
#define CHN 128        // chunks per batch
#define CHSZ 64        // points per chunk

// ---------------- ws layout (float offsets) ----------------
#define OFF_XYZW  0
#define OFF_PW1AT 131072
#define OFF_PW1BT 135168
#define OFF_PWVAT 139264
#define OFF_PWOT  143360
#define OFF_RELW  147456
#define OFF_STATS 147840
#define OFF_IDX   148224      // idx: 32768*16 ints (SORTED-space neighbor ids)
#define OFF_OPRE  672512      // [32768][64] o_pre, ORIGINAL layout (old OUTV region)
#define OFF_SX4   2769664     // sorted xyzw [4][8192] float4
#define OFF_SID   2900736     // sorted->orig ids [4][8192] int
#define OFF_HIST  2933504     // [4][4096] int
#define OFF_RANK  2950912     // orig->sorted rank [4][8192] int
#define OFF_PH    2983680     // PH2 [256][256] + PO2 [256][128] contiguous
#define OFF_BB    3606272     // bbmin[512] f4 (2048) + bbmax[512] f4 (2048)
#define OFF_F1    4866816     // SORTED layout [32768][64]
#define OFF_FZ    6963968     // SORTED layout [32768][64][2] = interleaved {F2,FV}

__device__ __forceinline__ int morton_cell(float x, float y, float z) {
    int cx = (int)floorf((x + 4.f) * 2.f);
    int cy = (int)floorf((y + 4.f) * 2.f);
    int cz = (int)floorf((z + 4.f) * 2.f);
    cx = cx < 0 ? 0 : (cx > 15 ? 15 : cx);
    cy = cy < 0 ? 0 : (cy > 15 ? 15 : cy);
    cz = cz < 0 ? 0 : (cz > 15 ? 15 : cz);
    int ex = (cx & 1) | ((cx & 2) << 2) | ((cx & 4) << 4) | ((cx & 8) << 6);
    int ey = (cy & 1) | ((cy & 2) << 2) | ((cy & 4) << 4) | ((cy & 8) << 6);
    int ez = (cz & 1) | ((cz & 2) << 2) | ((cz & 4) << 4) | ((cz & 8) << 6);
    return ex | (ey << 1) | (ez << 2);
}

__device__ __forceinline__ float distf(float4 me, float jx, float jy, float jz, float jw) {
    float dot = fmaf(me.z, jz, fmaf(me.y, jy, me.x * jx));
    return fmaf(-2.f, dot, me.w) + jw;
}

__device__ __forceinline__ float mind2(float4 me, float4 bmin, float4 bmax) {
    float dx = fmaxf(fmaxf(bmin.x - me.x, me.x - bmax.x), 0.f);
    float dy = fmaxf(fmaxf(bmin.y - me.y, me.y - bmax.y), 0.f);
    float dz = fmaxf(fmaxf(bmin.z - me.z, me.z - bmax.z), 0.f);
    return fmaf(dx, dx, fmaf(dy, dy, dz * dz));
}

__device__ __forceinline__ int mbcnt64(unsigned long long m) {
    return __builtin_amdgcn_mbcnt_hi((unsigned int)(m >> 32),
           __builtin_amdgcn_mbcnt_lo((unsigned int)m, 0));
}

__device__ __forceinline__ unsigned long long shflx_u64(unsigned long long v, int m) {
    int lo = __shfl_xor((int)(unsigned int)v, m, 64);
    int hi = __shfl_xor((int)(unsigned int)(v >> 32), m, 64);
    return ((unsigned long long)(unsigned int)hi << 32) | (unsigned int)lo;
}

// Round-8: blocks 0..127 point prep, block 128 weight transpose, blocks
// 129..224 zero the PH2+PO2 region (replaces one hipMemsetAsync).
__global__ __launch_bounds__(256) void k_prep(
    const float* __restrict__ xyz, const float* __restrict__ W1,
    const float* __restrict__ Wv, const float* __restrict__ Wo,
    float* __restrict__ xyzw, int* __restrict__ hist,
    float* __restrict__ pw1aT, float* __restrict__ pw1bT,
    float* __restrict__ pwvaT, float* __restrict__ pwoT, float* __restrict__ relw,
    float* __restrict__ stats, float* __restrict__ ph2)
{
    int t = threadIdx.x;
    int bid = blockIdx.x;
    if (bid < 128) {
        int pt = bid * 256 + t;
        int b = pt >> 13, n = pt & 8191;
        const float* xb = xyz + (unsigned)b * 3 * NN;
        float x = xb[n], y = xb[NN + n], z = xb[2 * NN + n];
        float sq = __fadd_rn(__fadd_rn(__fmul_rn(x, x), __fmul_rn(y, y)), __fmul_rn(z, z));
        ((float4*)xyzw)[pt] = make_float4(x, y, z, sq);
        atomicAdd(&hist[b * NCELL + morton_cell(x, y, z)], 1);
    } else if (bid == 128) {
        for (int e = t; e < 4096; e += 256) {
            int c = e >> 6, o = e & 63;
            pw1aT[e] = W1[o * 131 + c];
            pw1bT[e] = W1[o * 131 + 64 + c];
            pwvaT[e] = Wv[o * 67 + c];
            pwoT[e]  = Wo[o * 64 + c];
        }
        for (int e = t; e < 384; e += 256) {
            int d = e >> 6, o = e & 63;
            relw[e] = (d < 3) ? W1[o * 131 + 128 + d] : Wv[o * 67 + 64 + (d - 3)];
            stats[e] = 0.0f;
        }
    } else {
        // zero PH2+PO2: 98304 floats = 24576 float4; 96 blocks x 256 threads
        ((float4*)ph2)[(bid - 129) * 256 + t] = make_float4(0.f, 0.f, 0.f, 0.f);
    }
}

// Exclusive scan of per-batch 4096-bin histogram (in place), one block per batch.
__global__ __launch_bounds__(256) void k_scan(int* __restrict__ hist) {
    __shared__ int part[256];
    int b = blockIdx.x, t = threadIdx.x;
    int* h = hist + b * NCELL;
    int loc[16]; int s = 0;
#pragma unroll
    for (int i = 0; i < 16; i++) { loc[i] = h[t * 16 + i]; s += loc[i]; }
    part[t] = s;
    __syncthreads();
    for (int off = 1; off < 256; off <<= 1) {
        int v = (t >= off) ? part[t - off] : 0;
        __syncthreads();
        part[t] += v;
        __syncthreads();
    }
    int run = (t > 0) ? part[t - 1] : 0;
#pragma unroll
    for (int i = 0; i < 16; i++) { int c = loc[i]; h[t * 16 + i] = run; run += c; }
}

__global__ __launch_bounds__(256) void k_scatter(
    const float4* __restrict__ xyzw, int* __restrict__ off,
    float4* __restrict__ sx4, int* __restrict__ sid, int* __restrict__ rank)
{
    int pt = blockIdx.x * 256 + threadIdx.x;
    int b = pt >> 13, n = pt & 8191;
    float4 p = xyzw[pt];
    int cell = morton_cell(p.x, p.y, p.z);
    int dst = atomicAdd(&off[b * NCELL + cell], 1);
    sx4[(b << 13) + dst] = p;
    sid[(b << 13) + dst] = n;
    rank[pt] = dst;
}

// Per-point GEMVs (blocks 0..511), output scattered to SORTED layout via rank.
// F2/FV written INTERLEAVED per channel (FZ[pt][c] = {f2,fv}) so the gather
// kernels read one float2 per neighbor instead of two floats (round-8).
// Blocks 512..639: per-chunk bbox (fused former k_bbox; independent work).
__global__ __launch_bounds__(256) void k_F(
    const float* __restrict__ feats, const float* __restrict__ b1, const float* __restrict__ bv,
    const float* __restrict__ pw1aT, const float* __restrict__ pw1bT, const float* __restrict__ pwvaT,
    const int* __restrict__ rank,
    float* __restrict__ F1, float2* __restrict__ FZ,
    const float4* __restrict__ sx4, float4* __restrict__ bbmin, float4* __restrict__ bbmax)
{
    int t = threadIdx.x;
    int lane = t & 63;
    int wave = t >> 6;
    if (blockIdx.x >= 512) {
        // bbox over 64 sorted points; one wave per chunk
        int ch = (blockIdx.x - 512) * 4 + wave;   // 0..511
        float4 p = sx4[ch * CHSZ + lane];
        float mnx = p.x, mny = p.y, mnz = p.z, mxx = p.x, mxy = p.y, mxz = p.z;
#pragma unroll
        for (int o = 32; o >= 1; o >>= 1) {
            mnx = fminf(mnx, __shfl_xor(mnx, o, 64)); mxx = fmaxf(mxx, __shfl_xor(mxx, o, 64));
            mny = fminf(mny, __shfl_xor(mny, o, 64)); mxy = fmaxf(mxy, __shfl_xor(mxy, o, 64));
            mnz = fminf(mnz, __shfl_xor(mnz, o, 64)); mxz = fmaxf(mxz, __shfl_xor(mxz, o, 64));
        }
        if (lane == 0) {
            bbmin[ch] = make_float4(mnx, mny, mnz, 0.f);
            bbmax[ch] = make_float4(mxx, mxy, mxz, 0.f);
        }
        return;
    }
    int pt0 = blockIdx.x * 64 + wave * 16;
    int b   = __builtin_amdgcn_readfirstlane(pt0 >> 13);
    int n0  = __builtin_amdgcn_readfirstlane(pt0 & 8191);
    const float* fb = feats + (unsigned)b * CC * NN;
    float accA[16], accB[16], accV[16];
    float bb1 = b1[lane], bbv = bv[lane];
#pragma unroll
    for (int p = 0; p < 16; p++) { accA[p] = bb1; accB[p] = 0.f; accV[p] = bbv; }
    for (int c = 0; c < 64; c++) {
        float wA = pw1aT[c * 64 + lane];
        float wB = pw1bT[c * 64 + lane];
        float wV = pwvaT[c * 64 + lane];
        const float* fr = fb + (unsigned)c * NN + n0;
#pragma unroll
        for (int p = 0; p < 16; p++) {
            float f = fr[p];
            accA[p] = fmaf(wA, f, accA[p]);
            accB[p] = fmaf(wB, f, accB[p]);
            accV[p] = fmaf(wV, f, accV[p]);
        }
    }
#pragma unroll
    for (int p = 0; p < 16; p++) {
        unsigned dst = ((unsigned)b << 13) + (unsigned)rank[pt0 + p];  // wave-uniform
        F1[dst * 64u + lane] = accA[p];
        FZ[dst * 64u + lane] = make_float2(accB[p], accV[p]);
    }
}

// Fused KNN + fp64 refine + h/v BN-stats. ONE query per wave, XCD-swizzled.
// Proven r3 structure; round-8 change: stats phase reads interleaved FZ
// (one float2 gather per neighbor instead of two float gathers).
__global__ __launch_bounds__(128) void k_knn(
    const float4* __restrict__ sx4, const int* __restrict__ sid,
    const float4* __restrict__ bbmin, const float4* __restrict__ bbmax,
    const float* __restrict__ F1, const float2* __restrict__ FZ,
    const float* __restrict__ relw,
    int* __restrict__ idx, float* __restrict__ ph2)
{
    __shared__ int cand[2][CAP];
    int lane = threadIdx.x & 63;
    int wl = threadIdx.x >> 6;
    int bx = blockIdx.x;                       // 16384 blocks
    int vb = (bx & 7) * 2048 + (bx >> 3);      // XCD-aware swizzle (bijective)
    int gq = vb * 2 + wl;
    int b = __builtin_amdgcn_readfirstlane(gq >> 13);
    int qs = gq & 8191;
    const float4* sb = sx4 + ((unsigned)b << 13);
    const int* ib = sid + ((unsigned)b << 13);
    float4 me = sb[qs];                       // wave-uniform
    const float INF = 3.402823466e38f;
    int* wc = cand[wl];

    // early-issue long-latency loads (used only after the sort chains)
    float rw0 = relw[0 * 64 + lane], rw1 = relw[1 * 64 + lane], rw2 = relw[2 * 64 + lane];
    float rw3 = relw[3 * 64 + lane], rw4 = relw[4 * 64 + lane], rw5 = relw[5 * 64 + lane];
    float F1v = F1[(unsigned)gq * 64u + lane];
    float md0 = mind2(me, bbmin[b * CHN + lane], bbmax[b * CHN + lane]);
    float md1 = mind2(me, bbmin[b * CHN + 64 + lane], bbmax[b * CHN + 64 + lane]);

    // phase 1: positional window; values-only bitonic -> tau16
    int ws0 = qs - 32; ws0 = ws0 < 0 ? 0 : (ws0 > (NN - 64) ? (NN - 64) : ws0);
    float4 cp = sb[(unsigned)(ws0 + lane)];
    float d = distf(me, cp.x, cp.y, cp.z, cp.w);
    float s = d;
#pragma unroll
    for (int k2 = 2; k2 <= 64; k2 <<= 1) {
#pragma unroll
        for (int j2 = k2 >> 1; j2 >= 1; j2 >>= 1) {
            float o = __shfl_xor(s, j2, 64);
            bool wantMin = (((lane & j2) == 0) == ((lane & k2) == 0));
            s = wantMin ? fminf(s, o) : fmaxf(s, o);
        }
    }
    float tau = __int_as_float(__builtin_amdgcn_readlane(__float_as_int(s), 15));
    float tauA = tau * 1.0001f + 1e-5f;

    int cnt;
    {
        bool hit = (d <= tauA);
        unsigned long long hm = __ballot(hit);
        if (hit) wc[mbcnt64(hm)] = ws0 + lane;     // unsorted seed: same SET
        cnt = __popcll(hm);

        unsigned long long bm0 = __ballot(md0 <= tauA);
        unsigned long long bm1 = __ballot(md1 <= tauA);

        int c0 = -1;
        if (bm0)      { c0 = __builtin_ctzll(bm0); bm0 &= bm0 - 1; }
        else if (bm1) { c0 = 64 + __builtin_ctzll(bm1); bm1 &= bm1 - 1; }
        float4 p0 = make_float4(0.f, 0.f, 0.f, 0.f);
        if (c0 >= 0) p0 = sb[(unsigned)(c0 * CHSZ + lane)];
        while (c0 >= 0) {
            int c1 = -1;
            if (bm0)      { c1 = __builtin_ctzll(bm0); bm0 &= bm0 - 1; }
            else if (bm1) { c1 = 64 + __builtin_ctzll(bm1); bm1 &= bm1 - 1; }
            float4 p1 = p0;
            if (c1 >= 0) p1 = sb[(unsigned)(c1 * CHSZ + lane)];
            int pos = c0 * CHSZ + lane;
            float dd = distf(me, p0.x, p0.y, p0.z, p0.w);
            bool inwin = (pos >= ws0) && (pos < ws0 + 64);
            bool hit2 = (dd <= tauA) && !inwin;
            unsigned long long m2 = __ballot(hit2);
            if (hit2) {
                int slot = cnt + mbcnt64(m2);
                if (slot < CAP) wc[slot] = pos;
            }
            cnt += __popcll(m2);
            c0 = c1; p0 = p1;
        }
    }

    if (cnt > CAP) {
        // rare fallback: re-sort window WITH ids, verified sorted-insert top-32
        float fd = d; int cid = ws0 + lane;
#pragma unroll
        for (int k2 = 2; k2 <= 64; k2 <<= 1) {
#pragma unroll
            for (int j2 = k2 >> 1; j2 >= 1; j2 >>= 1) {
                float od = __shfl_xor(fd, j2, 64);
                int   oi = __shfl_xor(cid, j2, 64);
                bool wantMin = (((lane & j2) == 0) == ((lane & k2) == 0));
                bool to = wantMin ? (od < fd) : (od > fd);
                fd = to ? od : fd; cid = to ? oi : cid;
            }
        }
        bool lt32 = (lane < 32);
        float val = lt32 ? fd : INF;
        int vid = cid;
        float tau2 = __int_as_float(__builtin_amdgcn_readlane(__float_as_int(val), 31));
        float t2A = tau2 * 1.0001f + 1e-5f;
        unsigned long long fb0 = __ballot(md0 <= t2A);
        unsigned long long fb1 = __ballot(md1 <= t2A);
        while (fb0 | fb1) {
            int c;
            if (fb0) { c = __builtin_ctzll(fb0); fb0 &= fb0 - 1; }
            else     { c = 64 + __builtin_ctzll(fb1); fb1 &= fb1 - 1; }
            int pos = c * CHSZ + lane;
            float4 p = sb[(unsigned)pos];
            float dd = distf(me, p.x, p.y, p.z, p.w);
            bool inwin = (pos >= ws0) && (pos < ws0 + 64);
            dd = inwin ? INF : dd;
            unsigned long long m = __ballot(dd < tau2);
            while (m) {
                int hl = __builtin_ctzll(m); m &= m - 1;
                float dn = __int_as_float(
                    __builtin_amdgcn_readlane(__float_as_int(dd), hl));
                int jn = c * CHSZ + hl;
                unsigned long long bl = __ballot(val < dn);
                int pos2 = __popcll(bl);
                float sv = __shfl_up(val, 1, 64);
                int   sj = __shfl_up(vid, 1, 64);
                float nv = (lane > pos2) ? sv : val; nv = (lane == pos2) ? dn : nv;
                int   nj = (lane > pos2) ? sj : vid; nj = (lane == pos2) ? jn : nj;
                val = lt32 ? nv : val;
                vid = lt32 ? nj : vid;
                tau2 = __int_as_float(__builtin_amdgcn_readlane(__float_as_int(val), 31));
            }
        }
        if (lt32) wc[lane] = vid;
        cnt = 32;
    }

    // fp64 refine as single u64 key partial top-16 selection (16 stages)
    unsigned long long key;
    {
        double mx = (double)me.x, my = (double)me.y, mz = (double)me.z;
        double msq = (mx * mx + my * my) + mz * mz;
        if (lane < cnt) {
            int j = wc[lane];
            float4 cj = sb[(unsigned)j];
            double jx = (double)cj.x, jy = (double)cj.y, jz = (double)cj.z;
            double dot = (mx * jx + my * jy) + mz * jz;
            double sqj = (jx * jx + jy * jy) + jz * jz;
            double dd = (-2.0 * dot + msq) + sqj;
            dd = fmax(dd, 0.0);               // guard sign bit for u64 ordering
            unsigned long long pay = (unsigned long long)(unsigned int)((ib[j] << 13) | j);
            key = ((unsigned long long)__double_as_longlong(dd) & ~0x3FFFFFFULL) | pay;
        } else {
            key = (0x7FFULL << 52) | (unsigned int)lane;   // > any valid key, unique
        }
    }

#define CE(MASK, WMIN) do {                                                   \
        unsigned long long ok = shflx_u64(key, (MASK));                       \
        bool ol = ok < key;                                                   \
        bool tk = (WMIN) ? ol : !ol;                                          \
        key = tk ? ok : key;                                                  \
    } while (0)

    // stage A: sort 16-lane groups, alternating direction (10 exchanges)
#pragma unroll
    for (int k2 = 2; k2 <= 16; k2 <<= 1) {
#pragma unroll
        for (int j2 = k2 >> 1; j2 >= 1; j2 >>= 1) {
            bool wantMin = (((lane & j2) == 0) == ((lane & k2) == 0));
            CE(j2, wantMin);
        }
    }
    // stage B: bitonic halving: lanes 0..15 / 32..47 keep min-16
    CE(16, ((lane & 16) == 0));
    // stage C: sort the two bitonic 16-seqs ascending (4 exchanges)
#pragma unroll
    for (int j2 = 8; j2 >= 1; j2 >>= 1)
        CE(j2, ((lane & j2) == 0));
    // stage D: cross-merge sorted 16-sets: lane L (0..15) pairs with 47-L
    CE(47, true);
#undef CE

    int jw = (int)(key & 8191);               // sorted-space neighbor id (lanes 0..15)
    if (lane < 16) idx[(unsigned)gq * 16u + lane] = jw;

    // ---- fused h/v BN stats for this query's 16 neighbors (4-wide batches) ----
    unsigned gb = (unsigned)b << 13;
    float sh = 0.f, sh2 = 0.f, sv = 0.f, sv2 = 0.f;
#pragma unroll
    for (int kb = 0; kb < 4; kb++) {
        float4 cjA[4]; float2 fzA[4];
#pragma unroll
        for (int jj = 0; jj < 4; jj++) {
            int g = __builtin_amdgcn_readlane(jw, kb * 4 + jj);   // k-th neighbor id
            cjA[jj] = sb[(unsigned)g];
            fzA[jj] = FZ[(gb + (unsigned)g) * 64u + lane];
        }
#pragma unroll
        for (int jj = 0; jj < 4; jj++) {
            float rx = cjA[jj].x - me.x, ry = cjA[jj].y - me.y, rz = cjA[jj].z - me.z;
            float h = F1v + fzA[jj].x;
            h = fmaf(rw0, rx, h); h = fmaf(rw1, ry, h); h = fmaf(rw2, rz, h);
            float v = fzA[jj].y;
            v = fmaf(rw3, rx, v); v = fmaf(rw4, ry, v); v = fmaf(rw5, rz, v);
            sh += h; sh2 = fmaf(h, h, sh2);
            sv += v; sv2 = fmaf(v, v, sv2);
        }
    }
    float* bucket = ph2 + (unsigned)(bx & 255) * 256u;
    atomicAdd(&bucket[lane], sh);
    atomicAdd(&bucket[64 + lane], sh2);
    atomicAdd(&bucket[128 + lane], sv);
    atomicAdd(&bucket[192 + lane], sv2);
}

// Reduce PH2[256][256] -> stats[0..255]. 8 blocks; 8 atomics/addr.
__global__ __launch_bounds__(256) void k_red1(
    const float* __restrict__ ph2, float* __restrict__ stats)
{
    int t = threadIdx.x, p = blockIdx.x;
    float acc = 0.f;
    for (int i = 0; i < 32; i++)
        acc += ph2[(unsigned)(p * 32 + i) * 256u + t];
    atomicAdd(&stats[t], acc);
}

// Attention + fused Wo matvec + o-stats. SORTED space, XCD-swizzled.
// Round-8: FZ interleaved gathers (1 float2/neighbor); Wo matvec via
// readlane broadcast (no LDS, no lgkmcnt waits). Split-butterfly logit
// reduce retained from round-7 (bit-identical tree).
__global__ __launch_bounds__(256) void k_attn(
    const float4* __restrict__ sx4, const int* __restrict__ sid,
    const int* __restrict__ idx,
    const float* __restrict__ F1, const float2* __restrict__ FZ,
    const float* __restrict__ relw, const float* __restrict__ stats,
    const float* __restrict__ g1, const float* __restrict__ be1,
    const float* __restrict__ W2, const float* __restrict__ b2,
    const float* __restrict__ gv, const float* __restrict__ bev,
    const float* __restrict__ pwoT, const float* __restrict__ bo,
    float* __restrict__ opre, float* __restrict__ po2)
{
    int t = threadIdx.x;
    int lane = t & 63;
    int wl = t >> 6;
    int bx = blockIdx.x;                      // 8192 blocks
    int vb = (bx & 7) * 1024 + (bx >> 3);     // XCD-aware swizzle
    int gq = vb * 4 + wl;                     // sorted-global query
    const float invM = 1.f / 524288.f;
    float hm = stats[lane] * invM, hq = stats[64 + lane] * invM;
    float s1 = g1[lane] * rsqrtf(hq - hm * hm + EPSBN);
    float t1 = be1[lane] - s1 * hm;
    float vm = stats[128 + lane] * invM, vq = stats[192 + lane] * invM;
    float sv = gv[lane] * rsqrtf(vq - vm * vm + EPSBN);
    float tv = bev[lane] - sv * vm;
    float rw0 = relw[0 * 64 + lane], rw1 = relw[1 * 64 + lane], rw2 = relw[2 * 64 + lane];
    float rw3 = relw[3 * 64 + lane], rw4 = relw[4 * 64 + lane], rw5 = relw[5 * 64 + lane];
    float w2v = W2[lane];
    float b2v = b2[0];
    float bov = bo[lane];

    int b = __builtin_amdgcn_readfirstlane(gq >> 13);
    const float4* sb = sx4 + ((unsigned)b << 13);
    float4 me = sb[(unsigned)(gq & 8191)];
    float F1v = F1[(unsigned)gq * 64u + lane];
    unsigned orig = ((unsigned)b << 13) + (unsigned)sid[gq];   // wave-uniform
    const int* ip = idx + (unsigned)gq * 16u;
    unsigned gb = (unsigned)b << 13;
    float p[16], vk[16];
#pragma unroll
    for (int kb = 0; kb < 2; kb++) {
        float4 cjA[8]; float2 fzA[8];
#pragma unroll
        for (int jj = 0; jj < 8; jj++) {
            int gl = ip[kb * 8 + jj];
            cjA[jj] = sb[(unsigned)gl];
            fzA[jj] = FZ[(gb + (unsigned)gl) * 64u + lane];
        }
#pragma unroll
        for (int jj = 0; jj < 8; jj++) {
            int k = kb * 8 + jj;
            float rx = cjA[jj].x - me.x, ry = cjA[jj].y - me.y, rz = cjA[jj].z - me.z;
            float h = F1v + fzA[jj].x;
            h = fmaf(rw0, rx, h); h = fmaf(rw1, ry, h); h = fmaf(rw2, rz, h);
            float a = fmaxf(fmaf(s1, h, t1), 0.f);
            float v = fzA[jj].y;
            v = fmaf(rw3, rx, v); v = fmaf(rw4, ry, v); v = fmaf(rw5, rz, v);
            vk[k] = fmaxf(fmaf(sv, v, tv), 0.f);
            p[k] = w2v * a;                   // per-lane partial of logit k
        }
    }
    // split-butterfly multi-reduce: same tree as 6-stage xor butterfly per k.
    bool h32 = (lane & 32) != 0;
    float q8[8];
#pragma unroll
    for (int i = 0; i < 8; i++) {
        float send = h32 ? p[i] : p[8 + i];
        float recv = __shfl_xor(send, 32, 64);
        q8[i] = (h32 ? p[8 + i] : p[i]) + recv;
    }
    bool h16 = (lane & 16) != 0;
    float q4[4];
#pragma unroll
    for (int i = 0; i < 4; i++) {
        float send = h16 ? q8[i] : q8[4 + i];
        float recv = __shfl_xor(send, 16, 64);
        q4[i] = (h16 ? q8[4 + i] : q8[i]) + recv;
    }
    bool h8 = (lane & 8) != 0;
    float q2[2];
#pragma unroll
    for (int i = 0; i < 2; i++) {
        float send = h8 ? q4[i] : q4[2 + i];
        float recv = __shfl_xor(send, 8, 64);
        q2[i] = (h8 ? q4[2 + i] : q4[i]) + recv;
    }
    bool h4 = (lane & 4) != 0;
    float tt;
    {
        float send = h4 ? q2[0] : q2[1];
        float recv = __shfl_xor(send, 4, 64);
        tt = (h4 ? q2[1] : q2[0]) + recv;
    }
    tt += __shfl_xor(tt, 2, 64);
    tt += __shfl_xor(tt, 1, 64);
    float ek[16];
#pragma unroll
    for (int k = 0; k < 16; k++)
        ek[k] = __int_as_float(__builtin_amdgcn_readlane(__float_as_int(tt), 4 * k)) + b2v;

    float mx = ek[0];
#pragma unroll
    for (int k = 1; k < 16; k++) mx = fmaxf(mx, ek[k]);
    float ssum = 0.f;
#pragma unroll
    for (int k = 0; k < 16; k++) { float e = __expf(ek[k] - mx); ek[k] = e; ssum += e; }
    float acc = 0.f;
#pragma unroll
    for (int k = 0; k < 16; k++) acc = fmaf(ek[k], vk[k], acc);
    float ov = acc / ssum;

    // fused Wo matvec via readlane broadcast (no LDS); 4 accumulators
    float op0 = bov, op1 = 0.f, op2 = 0.f, op3 = 0.f;
#pragma unroll
    for (int c = 0; c < 64; c += 4) {
        op0 = fmaf(pwoT[(c + 0) * 64 + lane],
                   __int_as_float(__builtin_amdgcn_readlane(__float_as_int(ov), c + 0)), op0);
        op1 = fmaf(pwoT[(c + 1) * 64 + lane],
                   __int_as_float(__builtin_amdgcn_readlane(__float_as_int(ov), c + 1)), op1);
        op2 = fmaf(pwoT[(c + 2) * 64 + lane],
                   __int_as_float(__builtin_amdgcn_readlane(__float_as_int(ov), c + 2)), op2);
        op3 = fmaf(pwoT[(c + 3) * 64 + lane],
                   __int_as_float(__builtin_amdgcn_readlane(__float_as_int(ov), c + 3)), op3);
    }
    float op = (op0 + op1) + (op2 + op3);
    opre[orig * 64u + lane] = op;

    float* bucket = po2 + (unsigned)(bx & 255) * 128u;
    atomicAdd(&bucket[lane], op);
    atomicAdd(&bucket[64 + lane], op * op);
}

// Reduce PO2[256][128] -> stats[256..383]. 8 blocks; 8 atomics/addr.
__global__ __launch_bounds__(256) void k_red2(
    const float* __restrict__ po2, float* __restrict__ stats)
{
    int t = threadIdx.x, p = blockIdx.x;
    if (t < 128) {
        float acc = 0.f;
        for (int i = 0; i < 32; i++)
            acc += po2[(unsigned)(p * 32 + i) * 128u + t];
        atomicAdd(&stats[256 + t], acc);
    }
}

// Final: BN(o)+relu + residual feats, transpose [B,N,C]->[B,C,N]
__global__ __launch_bounds__(256) void k_final(
    const float* __restrict__ opre, const float* __restrict__ stats,
    const float* __restrict__ go, const float* __restrict__ beo,
    const float* __restrict__ feats, float* __restrict__ out)
{
    __shared__ float tile[64][65];
    int t = threadIdx.x;
    int blk = blockIdx.x;
    int b = blk >> 7, n0 = (blk & 127) << 6;
#pragma unroll
    for (int i = 0; i < 16; i++) {
        int e = t + i * 256;
        int r = e >> 6, c = e & 63;
        tile[r][c] = opre[(unsigned)((b << 13) + n0 + r) * 64u + c];
    }
    __syncthreads();
    const float invM = 1.f / 32768.f;
    int lane = t & 63, wv = t >> 6;
#pragma unroll
    for (int i = 0; i < 16; i++) {
        int c = wv * 16 + i;
        float om = stats[256 + c] * invM, oq = stats[320 + c] * invM;
        float so = go[c] * rsqrtf(oq - om * om + EPSBN);
        float to = beo[c] - so * om;
        float val = fmaxf(fmaf(so, tile[lane][c], to), 0.f);
        unsigned oix = ((unsigned)b * 64 + c) * NN + n0 + lane;
        out[oix] = val + feats[oix];
    }
}

extern "C" void kernel_launch(void* const* d_in, const int* in_sizes, int n_in,
                              void* d_out, int out_size, void* d_ws, size_t ws_size,
                              hipStream_t stream)
{
    const float* xyz  = (const float*)d_in[0];
    const float* feats= (const float*)d_in[1];
    const float* W1   = (const float*)d_in[2];
    const float* b1   = (const float*)d_in[3];
    const float* g1   = (const float*)d_in[4];
    const float* be1  = (const float*)d_in[5];
    const float* W2   = (const float*)d_in[6];
    const float* b2   = (const float*)d_in[7];
    const float* Wv   = (const float*)d_in[8];
    const float* bv   = (const float*)d_in[9];
    const float* gv   = (const float*)d_in[10];
    const float* bev  = (const float*)d_in[11];
    const float* Wo   = (const float*)d_in[12];
    const float* bo   = (const float*)d_in[13];
    const float* go   = (const float*)d_in[14];
    const float* beo  = (const float*)d_in[15];

    float* ws = (float*)d_ws;
    float* xyzw  = ws + OFF_XYZW;
    float* pw1aT = ws + OFF_PW1AT;
    float* pw1bT = ws + OFF_PW1BT;
    float* pwvaT = ws + OFF_PWVAT;
    float* pwoT  = ws + OFF_PWOT;
    float* relw  = ws + OFF_RELW;
    float* stats = ws + OFF_STATS;
    int*   idx   = (int*)(ws + OFF_IDX);
    float* opre  = ws + OFF_OPRE;
    float4* sx4  = (float4*)(ws + OFF_SX4);
    int*   sid   = (int*)(ws + OFF_SID);
    int*   hist  = (int*)(ws + OFF_HIST);
    float4* bbmn = (float4*)(ws + OFF_BB);
    float4* bbmx = (float4*)(ws + OFF_BB + 2048);
    int*   rank  = (int*)(ws + OFF_RANK);
    float* ph2   = ws + OFF_PH;
    float* po2   = ws + OFF_PH + 65536;
    float* F1    = ws + OFF_F1;
    float2* FZ   = (float2*)(ws + OFF_FZ);

    hipMemsetAsync(hist, 0, BB * NCELL * sizeof(int), stream);
    k_prep<<<225, 256, 0, stream>>>(xyz, W1, Wv, Wo, xyzw, hist,
                                    pw1aT, pw1bT, pwvaT, pwoT, relw, stats, ph2);
    k_scan<<<4, 256, 0, stream>>>(hist);
    k_scatter<<<128, 256, 0, stream>>>((const float4*)xyzw, hist, sx4, sid, rank);
    k_F<<<640, 256, 0, stream>>>(feats, b1, bv, pw1aT, pw1bT, pwvaT, rank, F1, FZ,
                                 (const float4*)sx4, bbmn, bbmx);
    k_knn<<<NPTS / 2, 128, 0, stream>>>((const float4*)sx4, sid, bbmn, bbmx,
                                        F1, (const float2*)FZ, relw, idx, ph2);
    k_red1<<<8, 256, 0, stream>>>(ph2, stats);
    k_attn<<<8192, 256, 0, stream>>>((const float4*)sx4, sid, idx, F1, (const float2*)FZ,
                                     relw, stats, g1, be1, W2, b2, gv, bev, pwoT, bo,
                                     opre, po2);
    k_red2<<<8, 256, 0, stream>>>(po2, stats);
    k_final<<<512, 256, 0, stream>>>(opre, stats, go, beo, feats, (float*)d_out);
}